// Round 2
// baseline (7316.799 us; speedup 1.0000x reference)
//
#include <hip/hip_runtime.h>

#define TPB 256
typedef unsigned int uint;
typedef unsigned short ushort;

__device__ __forceinline__ float bf2f(ushort h) {
  return __uint_as_float(((uint)h) << 16);
}
__device__ __forceinline__ ushort f2bf(float f) {
  uint u = __float_as_uint(f);
  u += 0x7fffu + ((u >> 16) & 1u);
  return (ushort)(u >> 16);
}

// ---------------- counting / scaling ----------------
__global__ __launch_bounds__(TPB) void count_k(const int* __restrict__ idx, int E,
                                               int* __restrict__ cnt) {
  int i = blockIdx.x * blockDim.x + threadIdx.x;
  if (i < E) atomicAdd(&cnt[idx[i]], 1);
}

__global__ __launch_bounds__(TPB) void rinv_k(const int* __restrict__ cnt, int n, float scale,
                                              float* __restrict__ rinv) {
  int i = blockIdx.x * blockDim.x + threadIdx.x;
  if (i < n) rinv[i] = scale / fmaxf((float)cnt[i], 1.0f);
}

__global__ __launch_bounds__(TPB) void avg2_k(const float* __restrict__ a,
                                              const float* __restrict__ b,
                                              float* __restrict__ o, int n) {
  int i = blockIdx.x * blockDim.x + threadIdx.x;
  if (i < n) o[i] = 0.5f * (a[i] + b[i]);
}

// ---------------- scatter-add of rinv-scaled 128-wide rows ----------------
// acc[sidx[e]][:] += x[gidx[e]][:] * rinv[sidx[e]]   (32 threads per edge, float4 each)
__global__ __launch_bounds__(TPB) void scatter128_k(const float* __restrict__ x,
                                                    const int* __restrict__ gidx,
                                                    const int* __restrict__ sidx,
                                                    const float* __restrict__ rinv,
                                                    int E, float* __restrict__ acc) {
  long long i = (long long)blockIdx.x * TPB + threadIdx.x;
  if (i >= ((long long)E << 5)) return;
  int e = (int)(i >> 5);
  int d = (int)(i & 31) << 2;
  int g = gidx[e];
  int sn = sidx[e];
  float r = rinv[sn];
  float4 v = *(const float4*)&x[((long long)g << 7) + d];
  float* p = &acc[((long long)sn << 7) + d];
  atomicAdd(p + 0, v.x * r);
  atomicAdd(p + 1, v.y * r);
  atomicAdd(p + 2, v.z * r);
  atomicAdd(p + 3, v.w * r);
}

// ---------------- fused multi-segment GEMM (+bias), N=128 ----------------
// out[row][:] = (bias?) + sum_s f(X_s[row][:]) @ W_s     f = relu if XRELU
// block: 256 threads -> 64 rows x 128 cols; thread: 4 rows x 8 cols
template <bool XB16, bool XRELU, bool OB16>
__global__ __launch_bounds__(TPB) void combine_k(
    const void* __restrict__ X0v, const float* __restrict__ W0, int K0,
    const void* __restrict__ X1v, const float* __restrict__ W1, int K1,
    int nseg, const float* __restrict__ bias, void* outv, int M) {
  __shared__ float lds_w[64 * 128];  // 32 KiB W-chunk
  const int t = threadIdx.x;
  const int c0 = (t & 15) << 3;
  const long long rbase = (long long)blockIdx.x * 64 + ((t >> 4) << 2);

  float acc[4][8];
#pragma unroll
  for (int r = 0; r < 4; ++r)
#pragma unroll
    for (int c = 0; c < 8; ++c) acc[r][c] = bias ? bias[c0 + c] : 0.0f;

  for (int s = 0; s < nseg; ++s) {
    const void* Xv = s ? X1v : X0v;
    const float* W = s ? W1 : W0;
    const int K = s ? K1 : K0;
    for (int k0 = 0; k0 < K; k0 += 64) {
      __syncthreads();
#pragma unroll
      for (int i = 0; i < 8; ++i) {
        int idx4 = t + i * TPB;           // 0..2047 float4s
        int kr = idx4 >> 5;               // 0..63
        int cc = (idx4 & 31) << 2;        // 0..124
        *(float4*)&lds_w[kr * 128 + cc] =
            *(const float4*)&W[(long long)(k0 + kr) * 128 + cc];
      }
      __syncthreads();

      for (int kk = 0; kk < 64; kk += 4) {
        float xs[4][4];
#pragma unroll
        for (int r = 0; r < 4; ++r) {
          long long row = rbase + r;
          if (row < M) {
            if (XB16) {
              ushort4 u = *(const ushort4*)((const ushort*)Xv + row * K + (k0 + kk));
              xs[r][0] = bf2f(u.x); xs[r][1] = bf2f(u.y);
              xs[r][2] = bf2f(u.z); xs[r][3] = bf2f(u.w);
            } else {
              float4 v = *(const float4*)((const float*)Xv + row * K + (k0 + kk));
              xs[r][0] = v.x; xs[r][1] = v.y; xs[r][2] = v.z; xs[r][3] = v.w;
            }
            if (XRELU) {
#pragma unroll
              for (int j = 0; j < 4; ++j) xs[r][j] = fmaxf(xs[r][j], 0.0f);
            }
          } else {
#pragma unroll
            for (int j = 0; j < 4; ++j) xs[r][j] = 0.0f;
          }
        }
#pragma unroll
        for (int j = 0; j < 4; ++j) {
          float4 wa = *(float4*)&lds_w[(kk + j) * 128 + c0];
          float4 wb = *(float4*)&lds_w[(kk + j) * 128 + c0 + 4];
#pragma unroll
          for (int r = 0; r < 4; ++r) {
            float x = xs[r][j];
            acc[r][0] = fmaf(x, wa.x, acc[r][0]);
            acc[r][1] = fmaf(x, wa.y, acc[r][1]);
            acc[r][2] = fmaf(x, wa.z, acc[r][2]);
            acc[r][3] = fmaf(x, wa.w, acc[r][3]);
            acc[r][4] = fmaf(x, wb.x, acc[r][4]);
            acc[r][5] = fmaf(x, wb.y, acc[r][5]);
            acc[r][6] = fmaf(x, wb.z, acc[r][6]);
            acc[r][7] = fmaf(x, wb.w, acc[r][7]);
          }
        }
      }
    }
  }

#pragma unroll
  for (int r = 0; r < 4; ++r) {
    long long row = rbase + r;
    if (row >= M) continue;
    if (OB16) {
      uint4 p;
      p.x = (uint)f2bf(acc[r][0]) | ((uint)f2bf(acc[r][1]) << 16);
      p.y = (uint)f2bf(acc[r][2]) | ((uint)f2bf(acc[r][3]) << 16);
      p.z = (uint)f2bf(acc[r][4]) | ((uint)f2bf(acc[r][5]) << 16);
      p.w = (uint)f2bf(acc[r][6]) | ((uint)f2bf(acc[r][7]) << 16);
      *(uint4*)((ushort*)outv + row * 128 + c0) = p;
    } else {
      float4 o0, o1;
      o0.x = acc[r][0]; o0.y = acc[r][1]; o0.z = acc[r][2]; o0.w = acc[r][3];
      o1.x = acc[r][4]; o1.y = acc[r][5]; o1.z = acc[r][6]; o1.w = acc[r][7];
      *(float4*)((float*)outv + row * 128 + c0) = o0;
      *(float4*)((float*)outv + row * 128 + c0 + 4) = o1;
    }
  }
}

// ---------------- final linear: relu(X) (M x 128) @ (128 x 16) + b ----------------
__global__ __launch_bounds__(TPB) void final_k(const float* __restrict__ X,
                                               const float* __restrict__ W,
                                               const float* __restrict__ b,
                                               float* __restrict__ out, int M) {
  __shared__ float lw[128 * 16];
  __shared__ float lb[16];
  int t = threadIdx.x;
  for (int i = t; i < 2048; i += TPB) lw[i] = W[i];
  if (t < 16) lb[t] = b[t];
  __syncthreads();
  long long row = (long long)blockIdx.x * TPB + t;
  if (row >= M) return;
  float acc[16];
#pragma unroll
  for (int c = 0; c < 16; ++c) acc[c] = lb[c];
  const float* xr = &X[row * 128];
  for (int k = 0; k < 128; k += 4) {
    float4 xv = *(const float4*)&xr[k];
    xv.x = fmaxf(xv.x, 0.f); xv.y = fmaxf(xv.y, 0.f);
    xv.z = fmaxf(xv.z, 0.f); xv.w = fmaxf(xv.w, 0.f);
#pragma unroll
    for (int j = 0; j < 4; ++j) {
      float xsc = (j == 0) ? xv.x : (j == 1) ? xv.y : (j == 2) ? xv.z : xv.w;
#pragma unroll
      for (int c = 0; c < 16; ++c) acc[c] = fmaf(xsc, lw[(k + j) * 16 + c], acc[c]);
    }
  }
#pragma unroll
  for (int c = 0; c < 16; c += 4) {
    float4 o; o.x = acc[c]; o.y = acc[c + 1]; o.z = acc[c + 2]; o.w = acc[c + 3];
    *(float4*)&out[row * 16 + c] = o;
  }
}

// ---------------- launch ----------------
extern "C" void kernel_launch(void* const* d_in, const int* in_sizes, int n_in,
                              void* d_out, int out_size, void* d_ws, size_t ws_size,
                              hipStream_t stream) {
  const float* xm = (const float*)d_in[0];
  const float* xc = (const float*)d_in[1];
  const float* xa = (const float*)d_in[2];
  const int* src_cm = (const int*)d_in[3];
  const int* dst_cm = (const int*)d_in[4];
  const int* src_am = (const int*)d_in[5];
  const int* dst_am = (const int*)d_in[6];
  const float* Wl_cm_0 = (const float*)d_in[7];
  const float* Wr_cm_0 = (const float*)d_in[8];
  const float* b_cm_0  = (const float*)d_in[9];
  const float* Wl_am_0 = (const float*)d_in[10];
  const float* Wr_am_0 = (const float*)d_in[11];
  const float* b_am_0  = (const float*)d_in[12];
  const float* Wl_mc_0 = (const float*)d_in[13];
  const float* Wr_mc_0 = (const float*)d_in[14];
  const float* b_mc_0  = (const float*)d_in[15];
  const float* Wl_ma_0 = (const float*)d_in[16];
  const float* Wr_ma_0 = (const float*)d_in[17];
  const float* b_ma_0  = (const float*)d_in[18];
  const float* Wl_cm_1 = (const float*)d_in[19];
  const float* Wr_cm_1 = (const float*)d_in[20];
  const float* b_cm_1  = (const float*)d_in[21];
  const float* Wl_am_1 = (const float*)d_in[22];
  const float* Wr_am_1 = (const float*)d_in[23];
  const float* b_am_1  = (const float*)d_in[24];
  const float* lin_W   = (const float*)d_in[31];
  const float* lin_b   = (const float*)d_in[32];

  const int NM = in_sizes[0] / 128;
  const int NC = in_sizes[1] / 64;
  const int NA = in_sizes[2] / 64;
  const int E  = in_sizes[3];
  const int SMAX = (NC > NA) ? NC : NA;

  // ---- workspace layout (float units) ----
  float* base = (float*)d_ws;
  size_t o = 0;
  float* A = base + o; o += (size_t)NM * 128;          // movie features (pre-relu), f32
  float* S = base + o; o += (size_t)SMAX * 128;        // reusable f32 scratch
  ushort* B = (ushort*)(base + o); o += (size_t)NC * 64;  // xc1 pre-relu, bf16
  ushort* C = (ushort*)(base + o); o += (size_t)NA * 64;  // xa1 pre-relu, bf16
  int* cnt_m_cm = (int*)(base + o); o += NM;
  int* cnt_m_am = (int*)(base + o); o += NM;
  int* cnt_c    = (int*)(base + o); o += NC;
  int* cnt_a    = (int*)(base + o); o += NA;
  float* rinv_m_cm = base + o; o += NM;
  float* rinv_m_am = base + o; o += NM;
  float* rinv_c    = base + o; o += NC;
  float* rinv_a    = base + o; o += NA;
  float* Wr0c = base + o; o += 128 * 128;
  float* b0c  = base + o; o += 128;
  float* Wr1c = base + o; o += 128 * 128;
  float* b1c  = base + o; o += 128;

  if (ws_size < o * sizeof(float)) return;  // diagnostic guard: fail via absmax, not fault

  float* outf = (float*)d_out;
  const int gE  = (E + TPB - 1) / TPB;
  const int gSC = (int)((((long long)E << 5) + TPB - 1) / TPB);

  // degree counts + reciprocal means (0.5 folds the HeteroConv mean over 2 movie rels)
  hipMemsetAsync(cnt_m_cm, 0, sizeof(int) * (size_t)(2 * NM + NC + NA), stream);
  count_k<<<gE, TPB, 0, stream>>>(dst_cm, E, cnt_m_cm);
  count_k<<<gE, TPB, 0, stream>>>(dst_am, E, cnt_m_am);
  count_k<<<gE, TPB, 0, stream>>>(src_cm, E, cnt_c);
  count_k<<<gE, TPB, 0, stream>>>(src_am, E, cnt_a);
  rinv_k<<<(NM + TPB - 1) / TPB, TPB, 0, stream>>>(cnt_m_cm, NM, 0.5f, rinv_m_cm);
  rinv_k<<<(NM + TPB - 1) / TPB, TPB, 0, stream>>>(cnt_m_am, NM, 0.5f, rinv_m_am);
  rinv_k<<<(NC + TPB - 1) / TPB, TPB, 0, stream>>>(cnt_c, NC, 1.0f, rinv_c);
  rinv_k<<<(NA + TPB - 1) / TPB, TPB, 0, stream>>>(cnt_a, NA, 1.0f, rinv_a);

  // pre-averaged movie Wr / bias per layer
  avg2_k<<<64, TPB, 0, stream>>>(Wr_cm_0, Wr_am_0, Wr0c, 16384);
  avg2_k<<<1, TPB, 0, stream>>>(b_cm_0, b_am_0, b0c, 128);
  avg2_k<<<64, TPB, 0, stream>>>(Wr_cm_1, Wr_am_1, Wr1c, 16384);
  avg2_k<<<1, TPB, 0, stream>>>(b_cm_1, b_am_1, b1c, 128);

  // ---- layer 0: crew  (scatter-first: agg_c = mean over rev-cm of xm) ----
  hipMemsetAsync(S, 0, sizeof(float) * (size_t)NC * 128, stream);
  scatter128_k<<<gSC, TPB, 0, stream>>>(xm, dst_cm, src_cm, rinv_c, E, S);
  combine_k<false, false, true><<<(NC + 63) / 64, TPB, 0, stream>>>(
      S, Wl_mc_0, 128, xc, Wr_mc_0, 64, 2, b_mc_0, B, NC);  // B = xc1 pre-relu (bf16)

  // ---- layer 0: cast ----
  hipMemsetAsync(S, 0, sizeof(float) * (size_t)NA * 128, stream);
  scatter128_k<<<gSC, TPB, 0, stream>>>(xm, dst_am, src_am, rinv_a, E, S);
  combine_k<false, false, true><<<(NA + 63) / 64, TPB, 0, stream>>>(
      S, Wl_ma_0, 128, xa, Wr_ma_0, 64, 2, b_ma_0, C, NA);  // C = xa1 pre-relu (bf16)

  // ---- layer 0: movies (GEMM-first: scatter transformed sources into A) ----
  combine_k<false, false, false><<<(NM + 63) / 64, TPB, 0, stream>>>(
      xm, Wr0c, 128, nullptr, nullptr, 0, 1, b0c, A, NM);   // A = xm@Wr0c + b0c
  combine_k<false, false, false><<<(NC + 63) / 64, TPB, 0, stream>>>(
      xc, Wl_cm_0, 64, nullptr, nullptr, 0, 1, nullptr, S, NC);  // S = xc@Wl_cm_0
  scatter128_k<<<gSC, TPB, 0, stream>>>(S, src_cm, dst_cm, rinv_m_cm, E, A);
  combine_k<false, false, false><<<(NA + 63) / 64, TPB, 0, stream>>>(
      xa, Wl_am_0, 64, nullptr, nullptr, 0, 1, nullptr, S, NA);  // S = xa@Wl_am_0
  scatter128_k<<<gSC, TPB, 0, stream>>>(S, src_am, dst_am, rinv_m_am, E, A);
  // A = xm1 pre-relu

  // ---- layer 1: movies only (crew/cast outputs dead) ----
  combine_k<false, true, false><<<(NM + 63) / 64, TPB, 0, stream>>>(
      A, Wr1c, 128, nullptr, nullptr, 0, 1, b1c, A, NM);    // A = relu(A)@Wr1c + b1c (in-place)
  combine_k<true, true, false><<<(NC + 63) / 64, TPB, 0, stream>>>(
      B, Wl_cm_1, 128, nullptr, nullptr, 0, 1, nullptr, S, NC);  // S = relu(B)@Wl_cm_1
  scatter128_k<<<gSC, TPB, 0, stream>>>(S, src_cm, dst_cm, rinv_m_cm, E, A);
  combine_k<true, true, false><<<(NA + 63) / 64, TPB, 0, stream>>>(
      C, Wl_am_1, 128, nullptr, nullptr, 0, 1, nullptr, S, NA);  // S = relu(C)@Wl_am_1
  scatter128_k<<<gSC, TPB, 0, stream>>>(S, src_am, dst_am, rinv_m_am, E, A);
  // A = xm2 pre-relu

  // ---- final linear ----
  final_k<<<(NM + TPB - 1) / TPB, TPB, 0, stream>>>(A, lin_W, lin_b, outf, NM);
}

// Round 5
// 1791.670 us; speedup vs baseline: 4.0838x; 4.0838x over previous
//
#include <hip/hip_runtime.h>

#define TPB 256
typedef unsigned int uint;
typedef unsigned short ushort;

__device__ __forceinline__ float bf2f(ushort h) {
  return __uint_as_float(((uint)h) << 16);
}
__device__ __forceinline__ ushort f2bf(float f) {
  uint u = __float_as_uint(f);
  u += 0x7fffu + ((u >> 16) & 1u);
  return (ushort)(u >> 16);
}

// ---------------- counting / scaling ----------------
__global__ __launch_bounds__(TPB) void count_k(const int* __restrict__ idx, int E,
                                               int* __restrict__ cnt) {
  int i = blockIdx.x * blockDim.x + threadIdx.x;
  if (i < E) atomicAdd(&cnt[idx[i]], 1);
}

__global__ __launch_bounds__(TPB) void rinv_k(const int* __restrict__ cnt, int n, float scale,
                                              float* __restrict__ rinv) {
  int i = blockIdx.x * blockDim.x + threadIdx.x;
  if (i < n) rinv[i] = scale / fmaxf((float)cnt[i], 1.0f);
}

__global__ __launch_bounds__(TPB) void avg2_k(const float* __restrict__ a,
                                              const float* __restrict__ b,
                                              float* __restrict__ o, int n) {
  int i = blockIdx.x * blockDim.x + threadIdx.x;
  if (i < n) o[i] = 0.5f * (a[i] + b[i]);
}

// ---------------- CSR build: blocksum -> scan blocksums -> finalize -> fill ----------------
__global__ __launch_bounds__(TPB) void blocksum_k(const int* __restrict__ cnt, int n,
                                                  int* __restrict__ bsum) {
  __shared__ int lds[TPB];
  int t = threadIdx.x;
  int i = blockIdx.x * TPB + t;
  lds[t] = (i < n) ? cnt[i] : 0;
  __syncthreads();
  for (int off = 128; off > 0; off >>= 1) {
    if (t < off) lds[t] += lds[t + off];
    __syncthreads();
  }
  if (t == 0) bsum[blockIdx.x] = lds[0];
}

// single block: exclusive scan of bsum[0..nb)
__global__ __launch_bounds__(TPB) void scanbsum_k(int* __restrict__ bsum, int nb) {
  __shared__ int lds[TPB];
  int t = threadIdx.x;
  int offset = 0;
  for (int base = 0; base < nb; base += TPB) {
    int v = (base + t < nb) ? bsum[base + t] : 0;
    lds[t] = v;
    __syncthreads();
    for (int off = 1; off < TPB; off <<= 1) {
      int add = (t >= off) ? lds[t - off] : 0;
      __syncthreads();
      lds[t] += add;
      __syncthreads();
    }
    int incl = lds[t];
    if (base + t < nb) bsum[base + t] = offset + incl - v;  // exclusive
    int tot = lds[TPB - 1];
    __syncthreads();
    offset += tot;
  }
}

// per-block local exclusive scan + block offset; writes rowptr and turns cnt into cursor
__global__ __launch_bounds__(TPB) void finalize_k(int* __restrict__ cnt, int n,
                                                  const int* __restrict__ bsum,
                                                  int* __restrict__ rowptr) {
  __shared__ int lds[TPB];
  int t = threadIdx.x;
  int i = blockIdx.x * TPB + t;
  int v = (i < n) ? cnt[i] : 0;
  lds[t] = v;
  __syncthreads();
  for (int off = 1; off < TPB; off <<= 1) {
    int add = (t >= off) ? lds[t - off] : 0;
    __syncthreads();
    lds[t] += add;
    __syncthreads();
  }
  int ex = lds[t] - v + bsum[blockIdx.x];
  if (i < n) {
    rowptr[i] = ex;
    cnt[i] = ex;                      // cursor for fill
    if (i == n - 1) rowptr[n] = ex + v;
  }
}

__global__ __launch_bounds__(TPB) void fill_k(const int* __restrict__ didx,
                                              const int* __restrict__ sidx, int E,
                                              int* __restrict__ cursor,
                                              int* __restrict__ perm) {
  int i = blockIdx.x * blockDim.x + threadIdx.x;
  if (i >= E) return;
  int d = didx[i];
  int pos = atomicAdd(&cursor[d], 1);
  perm[pos] = sidx[i];
}

// ---------------- CSR gather: out[n][:] (+)= rinv[n] * sum_{j in row(n)} x[perm[j]][:] ----
// 32 lanes per node (float4 per lane), 8 nodes per block, no atomics
template <bool ACCUM>
__global__ __launch_bounds__(TPB) void gather_k(const float* __restrict__ x,
                                                const int* __restrict__ rowptr,
                                                const int* __restrict__ perm,
                                                const float* __restrict__ rinv,
                                                int N, float* __restrict__ out) {
  int nid = blockIdx.x * 8 + (threadIdx.x >> 5);
  if (nid >= N) return;
  int d = (threadIdx.x & 31) << 2;
  int s0 = rowptr[nid], s1 = rowptr[nid + 1];
  float4 acc = make_float4(0.f, 0.f, 0.f, 0.f);
  for (int j = s0; j < s1; ++j) {
    int src = perm[j];
    float4 v = *(const float4*)&x[((long long)src << 7) + d];
    acc.x += v.x; acc.y += v.y; acc.z += v.z; acc.w += v.w;
  }
  float r = rinv[nid];
  float* p = &out[((long long)nid << 7) + d];
  if (ACCUM) {
    float4 cur = *(float4*)p;
    cur.x = fmaf(acc.x, r, cur.x);
    cur.y = fmaf(acc.y, r, cur.y);
    cur.z = fmaf(acc.z, r, cur.z);
    cur.w = fmaf(acc.w, r, cur.w);
    *(float4*)p = cur;
  } else {
    float4 o;
    o.x = acc.x * r; o.y = acc.y * r; o.z = acc.z * r; o.w = acc.w * r;
    *(float4*)p = o;
  }
}

// ---------------- fused multi-segment GEMM (+bias), N=128 ----------------
// out[row][:] = (bias?) + sum_s f(X_s[row][:]) @ W_s     f = relu if XRELU
// block: 256 threads -> 64 rows x 128 cols; thread: 4 rows x 8 cols
// Safe for in-place X0v==outv: each block touches only its own 64-row tile,
// and the __syncthreads() before the epilogue orders all X reads before writes.
template <bool XB16, bool XRELU, bool OB16>
__global__ __launch_bounds__(TPB) void combine_k(
    const void* __restrict__ X0v, const float* __restrict__ W0, int K0,
    const void* __restrict__ X1v, const float* __restrict__ W1, int K1,
    int nseg, const float* __restrict__ bias, void* outv, int M) {
  __shared__ float lds_w[64 * 128];  // 32 KiB W-chunk
  const int t = threadIdx.x;
  const int c0 = (t & 15) << 3;
  const long long rbase = (long long)blockIdx.x * 64 + ((t >> 4) << 2);

  float acc[4][8];
#pragma unroll
  for (int r = 0; r < 4; ++r)
#pragma unroll
    for (int c = 0; c < 8; ++c) acc[r][c] = bias ? bias[c0 + c] : 0.0f;

  for (int s = 0; s < nseg; ++s) {
    const void* Xv = s ? X1v : X0v;
    const float* W = s ? W1 : W0;
    const int K = s ? K1 : K0;
    for (int k0 = 0; k0 < K; k0 += 64) {
      __syncthreads();
#pragma unroll
      for (int i = 0; i < 8; ++i) {
        int idx4 = t + i * TPB;           // 0..2047 float4s
        int kr = idx4 >> 5;               // 0..63
        int cc = (idx4 & 31) << 2;        // 0..124
        *(float4*)&lds_w[kr * 128 + cc] =
            *(const float4*)&W[(long long)(k0 + kr) * 128 + cc];
      }
      __syncthreads();

      for (int kk = 0; kk < 64; kk += 4) {
        float xs[4][4];
#pragma unroll
        for (int r = 0; r < 4; ++r) {
          long long row = rbase + r;
          if (row < M) {
            if (XB16) {
              ushort4 u = *(const ushort4*)((const ushort*)Xv + row * K + (k0 + kk));
              xs[r][0] = bf2f(u.x); xs[r][1] = bf2f(u.y);
              xs[r][2] = bf2f(u.z); xs[r][3] = bf2f(u.w);
            } else {
              float4 v = *(const float4*)((const float*)Xv + row * K + (k0 + kk));
              xs[r][0] = v.x; xs[r][1] = v.y; xs[r][2] = v.z; xs[r][3] = v.w;
            }
            if (XRELU) {
#pragma unroll
              for (int j = 0; j < 4; ++j) xs[r][j] = fmaxf(xs[r][j], 0.0f);
            }
          } else {
#pragma unroll
            for (int j = 0; j < 4; ++j) xs[r][j] = 0.0f;
          }
        }
#pragma unroll
        for (int j = 0; j < 4; ++j) {
          float4 wa = *(float4*)&lds_w[(kk + j) * 128 + c0];
          float4 wb = *(float4*)&lds_w[(kk + j) * 128 + c0 + 4];
#pragma unroll
          for (int r = 0; r < 4; ++r) {
            float x = xs[r][j];
            acc[r][0] = fmaf(x, wa.x, acc[r][0]);
            acc[r][1] = fmaf(x, wa.y, acc[r][1]);
            acc[r][2] = fmaf(x, wa.z, acc[r][2]);
            acc[r][3] = fmaf(x, wa.w, acc[r][3]);
            acc[r][4] = fmaf(x, wb.x, acc[r][4]);
            acc[r][5] = fmaf(x, wb.y, acc[r][5]);
            acc[r][6] = fmaf(x, wb.z, acc[r][6]);
            acc[r][7] = fmaf(x, wb.w, acc[r][7]);
          }
        }
      }
    }
  }

  // Ensure every thread in the block has finished reading its X rows before
  // any thread overwrites them (required for in-place X0v == outv).
  __syncthreads();

#pragma unroll
  for (int r = 0; r < 4; ++r) {
    long long row = rbase + r;
    if (row >= M) continue;
    if (OB16) {
      uint4 p;
      p.x = (uint)f2bf(acc[r][0]) | ((uint)f2bf(acc[r][1]) << 16);
      p.y = (uint)f2bf(acc[r][2]) | ((uint)f2bf(acc[r][3]) << 16);
      p.z = (uint)f2bf(acc[r][4]) | ((uint)f2bf(acc[r][5]) << 16);
      p.w = (uint)f2bf(acc[r][6]) | ((uint)f2bf(acc[r][7]) << 16);
      *(uint4*)((ushort*)outv + row * 128 + c0) = p;
    } else {
      float4 o0, o1;
      o0.x = acc[r][0]; o0.y = acc[r][1]; o0.z = acc[r][2]; o0.w = acc[r][3];
      o1.x = acc[r][4]; o1.y = acc[r][5]; o1.z = acc[r][6]; o1.w = acc[r][7];
      *(float4*)((float*)outv + row * 128 + c0) = o0;
      *(float4*)((float*)outv + row * 128 + c0 + 4) = o1;
    }
  }
}

// ---------------- final linear: relu(X) (M x 128) @ (128 x 16) + b ----------------
__global__ __launch_bounds__(TPB) void final_k(const float* __restrict__ X,
                                               const float* __restrict__ W,
                                               const float* __restrict__ b,
                                               float* __restrict__ out, int M) {
  __shared__ float lw[128 * 16];
  __shared__ float lb[16];
  int t = threadIdx.x;
  for (int i = t; i < 2048; i += TPB) lw[i] = W[i];
  if (t < 16) lb[t] = b[t];
  __syncthreads();
  long long row = (long long)blockIdx.x * TPB + t;
  if (row >= M) return;
  float acc[16];
#pragma unroll
  for (int c = 0; c < 16; ++c) acc[c] = lb[c];
  const float* xr = &X[row * 128];
  for (int k = 0; k < 128; k += 4) {
    float4 xv = *(const float4*)&xr[k];
    xv.x = fmaxf(xv.x, 0.f); xv.y = fmaxf(xv.y, 0.f);
    xv.z = fmaxf(xv.z, 0.f); xv.w = fmaxf(xv.w, 0.f);
#pragma unroll
    for (int j = 0; j < 4; ++j) {
      float xsc = (j == 0) ? xv.x : (j == 1) ? xv.y : (j == 2) ? xv.z : xv.w;
#pragma unroll
      for (int c = 0; c < 16; ++c) acc[c] = fmaf(xsc, lw[(k + j) * 16 + c], acc[c]);
    }
  }
#pragma unroll
  for (int c = 0; c < 16; c += 4) {
    float4 o; o.x = acc[c]; o.y = acc[c + 1]; o.z = acc[c + 2]; o.w = acc[c + 3];
    *(float4*)&out[row * 16 + c] = o;
  }
}

// ---------------- launch ----------------
extern "C" void kernel_launch(void* const* d_in, const int* in_sizes, int n_in,
                              void* d_out, int out_size, void* d_ws, size_t ws_size,
                              hipStream_t stream) {
  const float* xm = (const float*)d_in[0];
  const float* xc = (const float*)d_in[1];
  const float* xa = (const float*)d_in[2];
  const int* src_cm = (const int*)d_in[3];
  const int* dst_cm = (const int*)d_in[4];
  const int* src_am = (const int*)d_in[5];
  const int* dst_am = (const int*)d_in[6];
  const float* Wl_cm_0 = (const float*)d_in[7];
  const float* Wr_cm_0 = (const float*)d_in[8];
  const float* b_cm_0  = (const float*)d_in[9];
  const float* Wl_am_0 = (const float*)d_in[10];
  const float* Wr_am_0 = (const float*)d_in[11];
  const float* b_am_0  = (const float*)d_in[12];
  const float* Wl_mc_0 = (const float*)d_in[13];
  const float* Wr_mc_0 = (const float*)d_in[14];
  const float* b_mc_0  = (const float*)d_in[15];
  const float* Wl_ma_0 = (const float*)d_in[16];
  const float* Wr_ma_0 = (const float*)d_in[17];
  const float* b_ma_0  = (const float*)d_in[18];
  const float* Wl_cm_1 = (const float*)d_in[19];
  const float* Wr_cm_1 = (const float*)d_in[20];
  const float* b_cm_1  = (const float*)d_in[21];
  const float* Wl_am_1 = (const float*)d_in[22];
  const float* Wr_am_1 = (const float*)d_in[23];
  const float* b_am_1  = (const float*)d_in[24];
  const float* lin_W   = (const float*)d_in[31];
  const float* lin_b   = (const float*)d_in[32];

  const int NM = in_sizes[0] / 128;
  const int NC = in_sizes[1] / 64;
  const int NA = in_sizes[2] / 64;
  const int E  = in_sizes[3];
  const int SMAX = (NC > NA) ? NC : NA;

  // ---- workspace layout (float units) ----
  float* base = (float*)d_ws;
  size_t o = 0;
  float* A = base + o; o += (size_t)NM * 128;             // movie features (pre-relu), f32
  float* S = base + o; o += (size_t)SMAX * 128;           // reusable f32 scratch
  ushort* B = (ushort*)(base + o); o += (size_t)NC * 64;  // xc1 pre-relu, bf16
  ushort* C = (ushort*)(base + o); o += (size_t)NA * 64;  // xa1 pre-relu, bf16
  int* cnt_m_cm = (int*)(base + o); o += NM;   // becomes fill cursor after finalize
  int* cnt_m_am = (int*)(base + o); o += NM;
  int* cnt_c    = (int*)(base + o); o += NC;
  int* cnt_a    = (int*)(base + o); o += NA;
  float* rinv_m_cm = base + o; o += NM;
  float* rinv_m_am = base + o; o += NM;
  float* rinv_c    = base + o; o += NC;
  float* rinv_a    = base + o; o += NA;
  int* rp_m_cm = (int*)(base + o); o += NM + 1;
  int* rp_m_am = (int*)(base + o); o += NM + 1;
  int* rp_c    = (int*)(base + o); o += NC + 1;
  int* rp_a    = (int*)(base + o); o += NA + 1;
  int* pm_m_cm = (int*)(base + o); o += E;
  int* pm_m_am = (int*)(base + o); o += E;
  int* pm_c    = (int*)(base + o); o += E;
  int* pm_a    = (int*)(base + o); o += E;
  int* bsum    = (int*)(base + o); o += 1024;
  float* Wr0c = base + o; o += 128 * 128;
  float* b0c  = base + o; o += 128;
  float* Wr1c = base + o; o += 128 * 128;
  float* b1c  = base + o; o += 128;

  if (ws_size < o * sizeof(float)) return;  // diagnostic guard: fail via absmax, not fault

  float* outf = (float*)d_out;
  const int gE = (E + TPB - 1) / TPB;

  // degree counts + reciprocal means (0.5 folds the HeteroConv mean over 2 movie rels)
  hipMemsetAsync(cnt_m_cm, 0, sizeof(int) * (size_t)(2 * NM + NC + NA), stream);
  count_k<<<gE, TPB, 0, stream>>>(dst_cm, E, cnt_m_cm);
  count_k<<<gE, TPB, 0, stream>>>(dst_am, E, cnt_m_am);
  count_k<<<gE, TPB, 0, stream>>>(src_cm, E, cnt_c);
  count_k<<<gE, TPB, 0, stream>>>(src_am, E, cnt_a);
  rinv_k<<<(NM + TPB - 1) / TPB, TPB, 0, stream>>>(cnt_m_cm, NM, 0.5f, rinv_m_cm);
  rinv_k<<<(NM + TPB - 1) / TPB, TPB, 0, stream>>>(cnt_m_am, NM, 0.5f, rinv_m_am);
  rinv_k<<<(NC + TPB - 1) / TPB, TPB, 0, stream>>>(cnt_c, NC, 1.0f, rinv_c);
  rinv_k<<<(NA + TPB - 1) / TPB, TPB, 0, stream>>>(cnt_a, NA, 1.0f, rinv_a);

  // pre-averaged movie Wr / bias per layer (THE round-3 regression: these were dropped)
  avg2_k<<<64, TPB, 0, stream>>>(Wr_cm_0, Wr_am_0, Wr0c, 16384);
  avg2_k<<<1, TPB, 0, stream>>>(b_cm_0, b_am_0, b0c, 128);
  avg2_k<<<64, TPB, 0, stream>>>(Wr_cm_1, Wr_am_1, Wr1c, 16384);
  avg2_k<<<1, TPB, 0, stream>>>(b_cm_1, b_am_1, b1c, 128);

  // CSR builds (sequential reuse of bsum scratch)
  struct Rel { int* cnt; int n; int* rp; const int* di; const int* si; int* pm; } rels[4] = {
      {cnt_m_cm, NM, rp_m_cm, dst_cm, src_cm, pm_m_cm},
      {cnt_m_am, NM, rp_m_am, dst_am, src_am, pm_m_am},
      {cnt_c,    NC, rp_c,    src_cm, dst_cm, pm_c},
      {cnt_a,    NA, rp_a,    src_am, dst_am, pm_a},
  };
  for (int r = 0; r < 4; ++r) {
    int nb = (rels[r].n + TPB - 1) / TPB;
    blocksum_k<<<nb, TPB, 0, stream>>>(rels[r].cnt, rels[r].n, bsum);
    scanbsum_k<<<1, TPB, 0, stream>>>(bsum, nb);
    finalize_k<<<nb, TPB, 0, stream>>>(rels[r].cnt, rels[r].n, bsum, rels[r].rp);
    fill_k<<<gE, TPB, 0, stream>>>(rels[r].di, rels[r].si, E, rels[r].cnt, rels[r].pm);
  }

  // ---- layer 0: crew  (gather movies over rev-cm, then 2-seg GEMM) ----
  gather_k<false><<<(NC + 7) / 8, TPB, 0, stream>>>(xm, rp_c, pm_c, rinv_c, NC, S);
  combine_k<false, false, true><<<(NC + 63) / 64, TPB, 0, stream>>>(
      S, Wl_mc_0, 128, xc, Wr_mc_0, 64, 2, b_mc_0, B, NC);  // B = xc1 pre-relu (bf16)

  // ---- layer 0: cast ----
  gather_k<false><<<(NA + 7) / 8, TPB, 0, stream>>>(xm, rp_a, pm_a, rinv_a, NA, S);
  combine_k<false, false, true><<<(NA + 63) / 64, TPB, 0, stream>>>(
      S, Wl_ma_0, 128, xa, Wr_ma_0, 64, 2, b_ma_0, C, NA);  // C = xa1 pre-relu (bf16)

  // ---- layer 0: movies (GEMM-first: gather transformed sources into A) ----
  combine_k<false, false, false><<<(NM + 63) / 64, TPB, 0, stream>>>(
      xm, Wr0c, 128, nullptr, nullptr, 0, 1, b0c, A, NM);   // A = xm@Wr0c + b0c
  combine_k<false, false, false><<<(NC + 63) / 64, TPB, 0, stream>>>(
      xc, Wl_cm_0, 64, nullptr, nullptr, 0, 1, nullptr, S, NC);  // S = xc@Wl_cm_0
  gather_k<true><<<(NM + 7) / 8, TPB, 0, stream>>>(S, rp_m_cm, pm_m_cm, rinv_m_cm, NM, A);
  combine_k<false, false, false><<<(NA + 63) / 64, TPB, 0, stream>>>(
      xa, Wl_am_0, 64, nullptr, nullptr, 0, 1, nullptr, S, NA);  // S = xa@Wl_am_0
  gather_k<true><<<(NM + 7) / 8, TPB, 0, stream>>>(S, rp_m_am, pm_m_am, rinv_m_am, NM, A);
  // A = xm1 pre-relu

  // ---- layer 1: movies only (crew/cast outputs dead) ----
  combine_k<false, true, false><<<(NM + 63) / 64, TPB, 0, stream>>>(
      A, Wr1c, 128, nullptr, nullptr, 0, 1, b1c, A, NM);    // A = relu(A)@Wr1c + b1c (in place)
  combine_k<true, true, false><<<(NC + 63) / 64, TPB, 0, stream>>>(
      B, Wl_cm_1, 128, nullptr, nullptr, 0, 1, nullptr, S, NC);  // S = relu(B)@Wl_cm_1
  gather_k<true><<<(NM + 7) / 8, TPB, 0, stream>>>(S, rp_m_cm, pm_m_cm, rinv_m_cm, NM, A);
  combine_k<true, true, false><<<(NA + 63) / 64, TPB, 0, stream>>>(
      C, Wl_am_1, 128, nullptr, nullptr, 0, 1, nullptr, S, NA);  // S = relu(C)@Wl_am_1
  gather_k<true><<<(NM + 7) / 8, TPB, 0, stream>>>(S, rp_m_am, pm_m_am, rinv_m_am, NM, A);
  // A = xm2 pre-relu

  // ---- final linear ----
  final_k<<<(NM + TPB - 1) / TPB, TPB, 0, stream>>>(A, lin_W, lin_b, outf, NM);
}

// Round 6
// 1117.184 us; speedup vs baseline: 6.5493x; 1.6037x over previous
//
#include <hip/hip_runtime.h>

#define TPB 256
typedef unsigned int uint;
typedef unsigned short ushort;
typedef __attribute__((ext_vector_type(8))) short bf16x8;
typedef __attribute__((ext_vector_type(8))) ushort u16x8;
typedef __attribute__((ext_vector_type(4))) float f32x4;

__device__ __forceinline__ ushort f2bf(float f) {
  uint u = __float_as_uint(f);
  u += 0x7fffu + ((u >> 16) & 1u);
  return (ushort)(u >> 16);
}

// ---------------- counting / scaling ----------------
__global__ __launch_bounds__(TPB) void count_k(const int* __restrict__ idx, int E,
                                               int* __restrict__ cnt) {
  int i = blockIdx.x * blockDim.x + threadIdx.x;
  if (i < E) atomicAdd(&cnt[idx[i]], 1);
}

__global__ __launch_bounds__(TPB) void rinv_k(const int* __restrict__ cnt, int n, float scale,
                                              float* __restrict__ rinv) {
  int i = blockIdx.x * blockDim.x + threadIdx.x;
  if (i < n) rinv[i] = scale / fmaxf((float)cnt[i], 1.0f);
}

__global__ __launch_bounds__(TPB) void avg2_k(const float* __restrict__ a,
                                              const float* __restrict__ b,
                                              float* __restrict__ o, int n) {
  int i = blockIdx.x * blockDim.x + threadIdx.x;
  if (i < n) o[i] = 0.5f * (a[i] + b[i]);
}

// transpose-convert weight (K x 128 f32, optionally averaged with b) -> (128 x K bf16)
__global__ __launch_bounds__(TPB) void wprep_k(const float* __restrict__ a,
                                               const float* __restrict__ b,
                                               int K, ushort* __restrict__ out) {
  int i = blockIdx.x * blockDim.x + threadIdx.x;
  int n = 128 * K;
  if (i >= n) return;
  int col = i / K, k = i - col * K;
  float v = a[k * 128 + col];
  if (b) v = 0.5f * (v + b[k * 128 + col]);
  out[i] = f2bf(v);
}

// ---------------- CSR build ----------------
__global__ __launch_bounds__(TPB) void blocksum_k(const int* __restrict__ cnt, int n,
                                                  int* __restrict__ bsum) {
  __shared__ int lds[TPB];
  int t = threadIdx.x;
  int i = blockIdx.x * TPB + t;
  lds[t] = (i < n) ? cnt[i] : 0;
  __syncthreads();
  for (int off = 128; off > 0; off >>= 1) {
    if (t < off) lds[t] += lds[t + off];
    __syncthreads();
  }
  if (t == 0) bsum[blockIdx.x] = lds[0];
}

__global__ __launch_bounds__(TPB) void scanbsum_k(int* __restrict__ bsum, int nb) {
  __shared__ int lds[TPB];
  int t = threadIdx.x;
  int offset = 0;
  for (int base = 0; base < nb; base += TPB) {
    int v = (base + t < nb) ? bsum[base + t] : 0;
    lds[t] = v;
    __syncthreads();
    for (int off = 1; off < TPB; off <<= 1) {
      int add = (t >= off) ? lds[t - off] : 0;
      __syncthreads();
      lds[t] += add;
      __syncthreads();
    }
    int incl = lds[t];
    if (base + t < nb) bsum[base + t] = offset + incl - v;
    int tot = lds[TPB - 1];
    __syncthreads();
    offset += tot;
  }
}

__global__ __launch_bounds__(TPB) void finalize_k(int* __restrict__ cnt, int n,
                                                  const int* __restrict__ bsum,
                                                  int* __restrict__ rowptr) {
  __shared__ int lds[TPB];
  int t = threadIdx.x;
  int i = blockIdx.x * TPB + t;
  int v = (i < n) ? cnt[i] : 0;
  lds[t] = v;
  __syncthreads();
  for (int off = 1; off < TPB; off <<= 1) {
    int add = (t >= off) ? lds[t - off] : 0;
    __syncthreads();
    lds[t] += add;
    __syncthreads();
  }
  int ex = lds[t] - v + bsum[blockIdx.x];
  if (i < n) {
    rowptr[i] = ex;
    cnt[i] = ex;
    if (i == n - 1) rowptr[n] = ex + v;
  }
}

__global__ __launch_bounds__(TPB) void fill_k(const int* __restrict__ didx,
                                              const int* __restrict__ sidx, int E,
                                              int* __restrict__ cursor,
                                              int* __restrict__ perm) {
  int i = blockIdx.x * blockDim.x + threadIdx.x;
  if (i >= E) return;
  int d = didx[i];
  int pos = atomicAdd(&cursor[d], 1);
  perm[pos] = sidx[i];
}

// ---------------- CSR gather ----------------
template <bool ACCUM>
__global__ __launch_bounds__(TPB) void gather_k(const float* __restrict__ x,
                                                const int* __restrict__ rowptr,
                                                const int* __restrict__ perm,
                                                const float* __restrict__ rinv,
                                                int N, float* __restrict__ out) {
  int nid = blockIdx.x * 8 + (threadIdx.x >> 5);
  if (nid >= N) return;
  int d = (threadIdx.x & 31) << 2;
  int s0 = rowptr[nid], s1 = rowptr[nid + 1];
  float4 acc = make_float4(0.f, 0.f, 0.f, 0.f);
  for (int j = s0; j < s1; ++j) {
    int src = perm[j];
    float4 v = *(const float4*)&x[((long long)src << 7) + d];
    acc.x += v.x; acc.y += v.y; acc.z += v.z; acc.w += v.w;
  }
  float r = rinv[nid];
  float* p = &out[((long long)nid << 7) + d];
  if (ACCUM) {
    float4 cur = *(float4*)p;
    cur.x = fmaf(acc.x, r, cur.x);
    cur.y = fmaf(acc.y, r, cur.y);
    cur.z = fmaf(acc.z, r, cur.z);
    cur.w = fmaf(acc.w, r, cur.w);
    *(float4*)p = cur;
  } else {
    float4 o;
    o.x = acc.x * r; o.y = acc.y * r; o.z = acc.z * r; o.w = acc.w * r;
    *(float4*)p = o;
  }
}

// ---------------- MFMA multi-segment GEMM (+bias), N=128 ----------------
// out[row][:] = bias + sum_s f(X_s[row][:]) @ W_s ; W given pre-transposed bf16 [128][K]
// block: 128 rows x 128 cols; 4 waves 2x2, each 64x64 via 4x4 16x16x32 frags.
// Safe in-place (X0v==outv): block reads exactly its own output rows;
// __syncthreads() before the epilogue orders reads before writes.
#define BK 64
#define XPITCH 72  // 64 + 8 pad (bf16 units): fragment ds_read_b128 at bank floor
template <bool XB16, bool XRELU, bool OB16>
__global__ __launch_bounds__(TPB) void mfma_combine_k(
    const void* __restrict__ X0v, const ushort* __restrict__ WT0, int K0,
    const void* __restrict__ X1v, const ushort* __restrict__ WT1, int K1,
    int nseg, const float* __restrict__ bias, void* __restrict__ outv, int M) {
  __shared__ ushort Xs[128 * XPITCH];
  __shared__ ushort Ws[128 * XPITCH];
  const int t = threadIdx.x;
  const int lane = t & 63;
  const int wid = t >> 6;
  const int wm = (wid >> 1) << 6;  // wave row offset (0/64)
  const int wn = (wid & 1) << 6;   // wave col offset (0/64)
  const long long rbase = (long long)blockIdx.x * 128;

  f32x4 acc[4][4];
#pragma unroll
  for (int mi = 0; mi < 4; ++mi)
#pragma unroll
    for (int ni = 0; ni < 4; ++ni) acc[mi][ni] = (f32x4){0.f, 0.f, 0.f, 0.f};

  for (int s = 0; s < nseg; ++s) {
    const void* Xv = s ? X1v : X0v;
    const ushort* WT = s ? WT1 : WT0;
    const int K = s ? K1 : K0;
    for (int k0 = 0; k0 < K; k0 += BK) {
      __syncthreads();
#pragma unroll
      for (int i = 0; i < 4; ++i) {
        int idx8 = t + i * TPB;        // 0..1023
        int row = idx8 >> 3;           // 0..127
        int kb = (idx8 & 7) << 3;      // 0..56
        // stage X (convert to bf16, fused relu)
        u16x8 xv;
        long long grow = rbase + row;
        if (grow < M) {
          if (XB16) {
            xv = *(const u16x8*)((const ushort*)Xv + grow * K + k0 + kb);
            if (XRELU) {
#pragma unroll
              for (int j = 0; j < 8; ++j) xv[j] = (xv[j] & 0x8000u) ? (ushort)0 : xv[j];
            }
          } else {
            const float* xp = (const float*)Xv + grow * K + k0 + kb;
            float4 a = *(const float4*)xp;
            float4 b = *(const float4*)(xp + 4);
            if (XRELU) {
              a.x = fmaxf(a.x, 0.f); a.y = fmaxf(a.y, 0.f);
              a.z = fmaxf(a.z, 0.f); a.w = fmaxf(a.w, 0.f);
              b.x = fmaxf(b.x, 0.f); b.y = fmaxf(b.y, 0.f);
              b.z = fmaxf(b.z, 0.f); b.w = fmaxf(b.w, 0.f);
            }
            xv[0] = f2bf(a.x); xv[1] = f2bf(a.y); xv[2] = f2bf(a.z); xv[3] = f2bf(a.w);
            xv[4] = f2bf(b.x); xv[5] = f2bf(b.y); xv[6] = f2bf(b.z); xv[7] = f2bf(b.w);
          }
        } else {
#pragma unroll
          for (int j = 0; j < 8; ++j) xv[j] = 0;
        }
        *(u16x8*)&Xs[row * XPITCH + kb] = xv;
        // stage W^T chunk (row here = output col)
        *(u16x8*)&Ws[row * XPITCH + kb] = *(const u16x8*)(WT + (long long)row * K + k0 + kb);
      }
      __syncthreads();
#pragma unroll
      for (int kk = 0; kk < BK; kk += 32) {
        const int krow = kk + ((lane >> 4) << 3);
        bf16x8 af[4], bf[4];
#pragma unroll
        for (int mi = 0; mi < 4; ++mi)
          af[mi] = *(const bf16x8*)&Xs[(wm + mi * 16 + (lane & 15)) * XPITCH + krow];
#pragma unroll
        for (int ni = 0; ni < 4; ++ni)
          bf[ni] = *(const bf16x8*)&Ws[(wn + ni * 16 + (lane & 15)) * XPITCH + krow];
#pragma unroll
        for (int mi = 0; mi < 4; ++mi)
#pragma unroll
          for (int ni = 0; ni < 4; ++ni)
            acc[mi][ni] = __builtin_amdgcn_mfma_f32_16x16x32_bf16(af[mi], bf[ni],
                                                                  acc[mi][ni], 0, 0, 0);
      }
    }
  }

  __syncthreads();  // in-place safety: all X reads complete before stores

  const int colbase = wn + (lane & 15);
  const int rsub = (lane >> 4) << 2;
#pragma unroll
  for (int ni = 0; ni < 4; ++ni) {
    int col = colbase + ni * 16;
    float bv = bias ? bias[col] : 0.f;
#pragma unroll
    for (int mi = 0; mi < 4; ++mi) {
      long long row0 = rbase + wm + mi * 16 + rsub;
#pragma unroll
      for (int j = 0; j < 4; ++j) {
        long long row = row0 + j;
        if (row < M) {
          float v = acc[mi][ni][j] + bv;
          if (OB16)
            ((ushort*)outv)[row * 128 + col] = f2bf(v);
          else
            ((float*)outv)[row * 128 + col] = v;
        }
      }
    }
  }
}

// ---------------- final linear: relu(X) (M x 128) @ (128 x 16) + b ----------------
__global__ __launch_bounds__(TPB) void final_k(const float* __restrict__ X,
                                               const float* __restrict__ W,
                                               const float* __restrict__ b,
                                               float* __restrict__ out, int M) {
  __shared__ float lw[128 * 16];
  __shared__ float lb[16];
  int t = threadIdx.x;
  for (int i = t; i < 2048; i += TPB) lw[i] = W[i];
  if (t < 16) lb[t] = b[t];
  __syncthreads();
  long long row = (long long)blockIdx.x * TPB + t;
  if (row >= M) return;
  float acc[16];
#pragma unroll
  for (int c = 0; c < 16; ++c) acc[c] = lb[c];
  const float* xr = &X[row * 128];
  for (int k = 0; k < 128; k += 4) {
    float4 xv = *(const float4*)&xr[k];
    xv.x = fmaxf(xv.x, 0.f); xv.y = fmaxf(xv.y, 0.f);
    xv.z = fmaxf(xv.z, 0.f); xv.w = fmaxf(xv.w, 0.f);
#pragma unroll
    for (int j = 0; j < 4; ++j) {
      float xsc = (j == 0) ? xv.x : (j == 1) ? xv.y : (j == 2) ? xv.z : xv.w;
#pragma unroll
      for (int c = 0; c < 16; ++c) acc[c] = fmaf(xsc, lw[(k + j) * 16 + c], acc[c]);
    }
  }
#pragma unroll
  for (int c = 0; c < 16; c += 4) {
    float4 o; o.x = acc[c]; o.y = acc[c + 1]; o.z = acc[c + 2]; o.w = acc[c + 3];
    *(float4*)&out[row * 16 + c] = o;
  }
}

// ---------------- launch ----------------
extern "C" void kernel_launch(void* const* d_in, const int* in_sizes, int n_in,
                              void* d_out, int out_size, void* d_ws, size_t ws_size,
                              hipStream_t stream) {
  const float* xm = (const float*)d_in[0];
  const float* xc = (const float*)d_in[1];
  const float* xa = (const float*)d_in[2];
  const int* src_cm = (const int*)d_in[3];
  const int* dst_cm = (const int*)d_in[4];
  const int* src_am = (const int*)d_in[5];
  const int* dst_am = (const int*)d_in[6];
  const float* Wl_cm_0 = (const float*)d_in[7];
  const float* Wr_cm_0 = (const float*)d_in[8];
  const float* b_cm_0  = (const float*)d_in[9];
  const float* Wl_am_0 = (const float*)d_in[10];
  const float* Wr_am_0 = (const float*)d_in[11];
  const float* b_am_0  = (const float*)d_in[12];
  const float* Wl_mc_0 = (const float*)d_in[13];
  const float* Wr_mc_0 = (const float*)d_in[14];
  const float* b_mc_0  = (const float*)d_in[15];
  const float* Wl_ma_0 = (const float*)d_in[16];
  const float* Wr_ma_0 = (const float*)d_in[17];
  const float* b_ma_0  = (const float*)d_in[18];
  const float* Wl_cm_1 = (const float*)d_in[19];
  const float* b_cm_1  = (const float*)d_in[21];
  const float* Wr_cm_1 = (const float*)d_in[20];
  const float* Wl_am_1 = (const float*)d_in[22];
  const float* Wr_am_1 = (const float*)d_in[23];
  const float* b_am_1  = (const float*)d_in[24];
  const float* lin_W   = (const float*)d_in[31];
  const float* lin_b   = (const float*)d_in[32];

  const int NM = in_sizes[0] / 128;
  const int NC = in_sizes[1] / 64;
  const int NA = in_sizes[2] / 64;
  const int E  = in_sizes[3];
  const int SMAX = (NC > NA) ? NC : NA;

  // ---- workspace layout (float units) ----
  float* base = (float*)d_ws;
  size_t o = 0;
  float* A = base + o; o += (size_t)NM * 128;             // movie features (pre-relu), f32
  float* S = base + o; o += (size_t)SMAX * 128;           // reusable f32 scratch
  ushort* B = (ushort*)(base + o); o += (size_t)NC * 64;  // xc1 pre-relu, bf16
  ushort* C = (ushort*)(base + o); o += (size_t)NA * 64;  // xa1 pre-relu, bf16
  int* cnt_m_cm = (int*)(base + o); o += NM;
  int* cnt_m_am = (int*)(base + o); o += NM;
  int* cnt_c    = (int*)(base + o); o += NC;
  int* cnt_a    = (int*)(base + o); o += NA;
  float* rinv_m_cm = base + o; o += NM;
  float* rinv_m_am = base + o; o += NM;
  float* rinv_c    = base + o; o += NC;
  float* rinv_a    = base + o; o += NA;
  int* rp_m_cm = (int*)(base + o); o += NM + 1;
  int* rp_m_am = (int*)(base + o); o += NM + 1;
  int* rp_c    = (int*)(base + o); o += NC + 1;
  int* rp_a    = (int*)(base + o); o += NA + 1;
  int* pm_m_cm = (int*)(base + o); o += E;
  int* pm_m_am = (int*)(base + o); o += E;
  int* pm_c    = (int*)(base + o); o += E;
  int* pm_a    = (int*)(base + o); o += E;
  int* bsum    = (int*)(base + o); o += 1024;
  float* b0c  = base + o; o += 128;
  float* b1c  = base + o; o += 128;
  // pre-transposed bf16 weights [128][K]
  ushort* WT_r0   = (ushort*)(base + o); o += 8192;  // avg(Wr_cm_0,Wr_am_0) K=128
  ushort* WT_r1   = (ushort*)(base + o); o += 8192;  // avg(Wr_cm_1,Wr_am_1) K=128
  ushort* WT_mc0l = (ushort*)(base + o); o += 8192;  // Wl_mc_0 K=128
  ushort* WT_ma0l = (ushort*)(base + o); o += 8192;  // Wl_ma_0 K=128
  ushort* WT_cm1  = (ushort*)(base + o); o += 8192;  // Wl_cm_1 K=128
  ushort* WT_am1  = (ushort*)(base + o); o += 8192;  // Wl_am_1 K=128
  ushort* WT_mc0r = (ushort*)(base + o); o += 4096;  // Wr_mc_0 K=64
  ushort* WT_ma0r = (ushort*)(base + o); o += 4096;  // Wr_ma_0 K=64
  ushort* WT_cm0  = (ushort*)(base + o); o += 4096;  // Wl_cm_0 K=64
  ushort* WT_am0  = (ushort*)(base + o); o += 4096;  // Wl_am_0 K=64

  if (ws_size < o * sizeof(float)) return;  // diagnostic guard

  float* outf = (float*)d_out;
  const int gE = (E + TPB - 1) / TPB;

  // degree counts + reciprocal means (0.5 folds HeteroConv mean over 2 movie rels)
  hipMemsetAsync(cnt_m_cm, 0, sizeof(int) * (size_t)(2 * NM + NC + NA), stream);
  count_k<<<gE, TPB, 0, stream>>>(dst_cm, E, cnt_m_cm);
  count_k<<<gE, TPB, 0, stream>>>(dst_am, E, cnt_m_am);
  count_k<<<gE, TPB, 0, stream>>>(src_cm, E, cnt_c);
  count_k<<<gE, TPB, 0, stream>>>(src_am, E, cnt_a);
  rinv_k<<<(NM + TPB - 1) / TPB, TPB, 0, stream>>>(cnt_m_cm, NM, 0.5f, rinv_m_cm);
  rinv_k<<<(NM + TPB - 1) / TPB, TPB, 0, stream>>>(cnt_m_am, NM, 0.5f, rinv_m_am);
  rinv_k<<<(NC + TPB - 1) / TPB, TPB, 0, stream>>>(cnt_c, NC, 1.0f, rinv_c);
  rinv_k<<<(NA + TPB - 1) / TPB, TPB, 0, stream>>>(cnt_a, NA, 1.0f, rinv_a);

  // averaged biases + bf16-transposed weights
  avg2_k<<<1, TPB, 0, stream>>>(b_cm_0, b_am_0, b0c, 128);
  avg2_k<<<1, TPB, 0, stream>>>(b_cm_1, b_am_1, b1c, 128);
  wprep_k<<<64, TPB, 0, stream>>>(Wr_cm_0, Wr_am_0, 128, WT_r0);
  wprep_k<<<64, TPB, 0, stream>>>(Wr_cm_1, Wr_am_1, 128, WT_r1);
  wprep_k<<<64, TPB, 0, stream>>>(Wl_mc_0, nullptr, 128, WT_mc0l);
  wprep_k<<<64, TPB, 0, stream>>>(Wl_ma_0, nullptr, 128, WT_ma0l);
  wprep_k<<<64, TPB, 0, stream>>>(Wl_cm_1, nullptr, 128, WT_cm1);
  wprep_k<<<64, TPB, 0, stream>>>(Wl_am_1, nullptr, 128, WT_am1);
  wprep_k<<<32, TPB, 0, stream>>>(Wr_mc_0, nullptr, 64, WT_mc0r);
  wprep_k<<<32, TPB, 0, stream>>>(Wr_ma_0, nullptr, 64, WT_ma0r);
  wprep_k<<<32, TPB, 0, stream>>>(Wl_cm_0, nullptr, 64, WT_cm0);
  wprep_k<<<32, TPB, 0, stream>>>(Wl_am_0, nullptr, 64, WT_am0);

  // CSR builds
  struct Rel { int* cnt; int n; int* rp; const int* di; const int* si; int* pm; } rels[4] = {
      {cnt_m_cm, NM, rp_m_cm, dst_cm, src_cm, pm_m_cm},
      {cnt_m_am, NM, rp_m_am, dst_am, src_am, pm_m_am},
      {cnt_c,    NC, rp_c,    src_cm, dst_cm, pm_c},
      {cnt_a,    NA, rp_a,    src_am, dst_am, pm_a},
  };
  for (int r = 0; r < 4; ++r) {
    int nb = (rels[r].n + TPB - 1) / TPB;
    blocksum_k<<<nb, TPB, 0, stream>>>(rels[r].cnt, rels[r].n, bsum);
    scanbsum_k<<<1, TPB, 0, stream>>>(bsum, nb);
    finalize_k<<<nb, TPB, 0, stream>>>(rels[r].cnt, rels[r].n, bsum, rels[r].rp);
    fill_k<<<gE, TPB, 0, stream>>>(rels[r].di, rels[r].si, E, rels[r].cnt, rels[r].pm);
  }

  const int gM = (NM + 127) / 128;
  const int gC = (NC + 127) / 128;
  const int gA = (NA + 127) / 128;

  // ---- layer 0: crew ----
  gather_k<false><<<(NC + 7) / 8, TPB, 0, stream>>>(xm, rp_c, pm_c, rinv_c, NC, S);
  mfma_combine_k<false, false, true><<<gC, TPB, 0, stream>>>(
      S, WT_mc0l, 128, xc, WT_mc0r, 64, 2, b_mc_0, B, NC);   // B = xc1 pre-relu (bf16)

  // ---- layer 0: cast ----
  gather_k<false><<<(NA + 7) / 8, TPB, 0, stream>>>(xm, rp_a, pm_a, rinv_a, NA, S);
  mfma_combine_k<false, false, true><<<gA, TPB, 0, stream>>>(
      S, WT_ma0l, 128, xa, WT_ma0r, 64, 2, b_ma_0, C, NA);   // C = xa1 pre-relu (bf16)

  // ---- layer 0: movies (GEMM-first; gather transformed sources into A) ----
  mfma_combine_k<false, false, false><<<gM, TPB, 0, stream>>>(
      xm, WT_r0, 128, nullptr, nullptr, 0, 1, b0c, A, NM);   // A = xm@Wr0c + b0c
  mfma_combine_k<false, false, false><<<gC, TPB, 0, stream>>>(
      xc, WT_cm0, 64, nullptr, nullptr, 0, 1, nullptr, S, NC);
  gather_k<true><<<(NM + 7) / 8, TPB, 0, stream>>>(S, rp_m_cm, pm_m_cm, rinv_m_cm, NM, A);
  mfma_combine_k<false, false, false><<<gA, TPB, 0, stream>>>(
      xa, WT_am0, 64, nullptr, nullptr, 0, 1, nullptr, S, NA);
  gather_k<true><<<(NM + 7) / 8, TPB, 0, stream>>>(S, rp_m_am, pm_m_am, rinv_m_am, NM, A);
  // A = xm1 pre-relu

  // ---- layer 1: movies only ----
  mfma_combine_k<false, true, false><<<gM, TPB, 0, stream>>>(
      A, WT_r1, 128, nullptr, nullptr, 0, 1, b1c, A, NM);    // in-place
  mfma_combine_k<true, true, false><<<gC, TPB, 0, stream>>>(
      B, WT_cm1, 128, nullptr, nullptr, 0, 1, nullptr, S, NC);
  gather_k<true><<<(NM + 7) / 8, TPB, 0, stream>>>(S, rp_m_cm, pm_m_cm, rinv_m_cm, NM, A);
  mfma_combine_k<true, true, false><<<gA, TPB, 0, stream>>>(
      C, WT_am1, 128, nullptr, nullptr, 0, 1, nullptr, S, NA);
  gather_k<true><<<(NM + 7) / 8, TPB, 0, stream>>>(S, rp_m_am, pm_m_am, rinv_m_am, NM, A);
  // A = xm2 pre-relu

  // ---- final linear ----
  final_k<<<(NM + TPB - 1) / TPB, TPB, 0, stream>>>(A, lin_W, lin_b, outf, NM);
}

// Round 7
// 1090.265 us; speedup vs baseline: 6.7110x; 1.0247x over previous
//
#include <hip/hip_runtime.h>

#define TPB 256
typedef unsigned int uint;
typedef unsigned short ushort;
typedef __attribute__((ext_vector_type(8))) short bf16x8;
typedef __attribute__((ext_vector_type(8))) ushort u16x8;
typedef __attribute__((ext_vector_type(4))) float f32x4;

__device__ __forceinline__ float bf2f(ushort h) {
  return __uint_as_float(((uint)h) << 16);
}
__device__ __forceinline__ ushort f2bf(float f) {
  uint u = __float_as_uint(f);
  u += 0x7fffu + ((u >> 16) & 1u);
  return (ushort)(u >> 16);
}

// ---------------- fused degree count: one dispatch, all 4 CSR histograms ----------------
__global__ __launch_bounds__(TPB) void count4_k(const int* __restrict__ src_cm,
                                                const int* __restrict__ dst_cm,
                                                const int* __restrict__ src_am,
                                                const int* __restrict__ dst_am,
                                                int E, int* __restrict__ cnt_m_cm,
                                                int* __restrict__ cnt_m_am,
                                                int* __restrict__ cnt_c,
                                                int* __restrict__ cnt_a) {
  int i = blockIdx.x * blockDim.x + threadIdx.x;
  if (i < E) {
    atomicAdd(&cnt_m_cm[dst_cm[i]], 1);
    atomicAdd(&cnt_c[src_cm[i]], 1);
  } else if (i < 2 * E) {
    int e = i - E;
    atomicAdd(&cnt_m_am[dst_am[e]], 1);
    atomicAdd(&cnt_a[src_am[e]], 1);
  }
}

// cnt block and rinv block are contiguous & same order: [m_cm NM][m_am NM][c NC][a NA]
__global__ __launch_bounds__(TPB) void rinvall_k(const int* __restrict__ cnt,
                                                 float* __restrict__ rinv,
                                                 int nm2, int total) {
  int i = blockIdx.x * blockDim.x + threadIdx.x;
  if (i < total) {
    float scale = (i < nm2) ? 0.5f : 1.0f;
    rinv[i] = scale / fmaxf((float)cnt[i], 1.0f);
  }
}

__global__ __launch_bounds__(TPB) void avg2_k(const float* __restrict__ a,
                                              const float* __restrict__ b,
                                              float* __restrict__ o, int n) {
  int i = blockIdx.x * blockDim.x + threadIdx.x;
  if (i < n) o[i] = 0.5f * (a[i] + b[i]);
}

// transpose-convert weight (K x 128 f32, optionally averaged with b) -> (128 x K bf16)
__global__ __launch_bounds__(TPB) void wprep_k(const float* __restrict__ a,
                                               const float* __restrict__ b,
                                               int K, ushort* __restrict__ out) {
  int i = blockIdx.x * blockDim.x + threadIdx.x;
  int n = 128 * K;
  if (i >= n) return;
  int col = i / K, k = i - col * K;
  float v = a[k * 128 + col];
  if (b) v = 0.5f * (v + b[k * 128 + col]);
  out[i] = f2bf(v);
}

// ---------------- CSR build (all 4 relations per dispatch) ----------------
__device__ __forceinline__ void rel_map(int b, int nb0, int nb1, int nb2, int nb3,
                                        int& r, int& lb) {
  if (b < nb0) { r = 0; lb = b; }
  else if (b < nb0 + nb1) { r = 1; lb = b - nb0; }
  else if (b < nb0 + nb1 + nb2) { r = 2; lb = b - nb0 - nb1; }
  else { r = 3; lb = b - nb0 - nb1 - nb2; }
}

__global__ __launch_bounds__(TPB) void blocksum_all_k(
    const int* __restrict__ c0, int n0, const int* __restrict__ c1, int n1,
    const int* __restrict__ c2, int n2, const int* __restrict__ c3, int n3,
    int* __restrict__ bsum) {
  __shared__ int lds[TPB];
  int nb0 = (n0 + TPB - 1) / TPB, nb1 = (n1 + TPB - 1) / TPB;
  int nb2 = (n2 + TPB - 1) / TPB, nb3 = (n3 + TPB - 1) / TPB;
  int r, lb;
  rel_map(blockIdx.x, nb0, nb1, nb2, nb3, r, lb);
  const int* cnt = (r == 0) ? c0 : (r == 1) ? c1 : (r == 2) ? c2 : c3;
  int n = (r == 0) ? n0 : (r == 1) ? n1 : (r == 2) ? n2 : n3;
  int t = threadIdx.x;
  int i = lb * TPB + t;
  lds[t] = (i < n) ? cnt[i] : 0;
  __syncthreads();
  for (int off = 128; off > 0; off >>= 1) {
    if (t < off) lds[t] += lds[t + off];
    __syncthreads();
  }
  if (t == 0) bsum[r * 1024 + lb] = lds[0];
}

// 4 blocks; block r does serial-chunked exclusive scan of bsum[r*1024 .. +nb)
__global__ __launch_bounds__(TPB) void scan_all_k(int* __restrict__ bsum,
                                                  int n0, int n1, int n2, int n3) {
  __shared__ int lds[TPB];
  int r = blockIdx.x;
  int n = (r == 0) ? n0 : (r == 1) ? n1 : (r == 2) ? n2 : n3;
  int nb = (n + TPB - 1) / TPB;
  int* bs = bsum + r * 1024;
  int t = threadIdx.x;
  int offset = 0;
  for (int base = 0; base < nb; base += TPB) {
    int v = (base + t < nb) ? bs[base + t] : 0;
    lds[t] = v;
    __syncthreads();
    for (int off = 1; off < TPB; off <<= 1) {
      int add = (t >= off) ? lds[t - off] : 0;
      __syncthreads();
      lds[t] += add;
      __syncthreads();
    }
    int incl = lds[t];
    if (base + t < nb) bs[base + t] = offset + incl - v;
    int tot = lds[TPB - 1];
    __syncthreads();
    offset += tot;
  }
}

__global__ __launch_bounds__(TPB) void finalize_all_k(
    int* __restrict__ c0, int n0, int* __restrict__ rp0,
    int* __restrict__ c1, int n1, int* __restrict__ rp1,
    int* __restrict__ c2, int n2, int* __restrict__ rp2,
    int* __restrict__ c3, int n3, int* __restrict__ rp3,
    const int* __restrict__ bsum) {
  __shared__ int lds[TPB];
  int nb0 = (n0 + TPB - 1) / TPB, nb1 = (n1 + TPB - 1) / TPB;
  int nb2 = (n2 + TPB - 1) / TPB, nb3 = (n3 + TPB - 1) / TPB;
  int r, lb;
  rel_map(blockIdx.x, nb0, nb1, nb2, nb3, r, lb);
  int* cnt = (r == 0) ? c0 : (r == 1) ? c1 : (r == 2) ? c2 : c3;
  int* rowptr = (r == 0) ? rp0 : (r == 1) ? rp1 : (r == 2) ? rp2 : rp3;
  int n = (r == 0) ? n0 : (r == 1) ? n1 : (r == 2) ? n2 : n3;
  int t = threadIdx.x;
  int i = lb * TPB + t;
  int v = (i < n) ? cnt[i] : 0;
  lds[t] = v;
  __syncthreads();
  for (int off = 1; off < TPB; off <<= 1) {
    int add = (t >= off) ? lds[t - off] : 0;
    __syncthreads();
    lds[t] += add;
    __syncthreads();
  }
  int ex = lds[t] - v + bsum[r * 1024 + lb];
  if (i < n) {
    rowptr[i] = ex;
    cnt[i] = ex;  // cursor for fill
    if (i == n - 1) rowptr[n] = ex + v;
  }
}

// one dispatch fills all 4 perm arrays (2E threads; each edge serves 2 CSRs)
__global__ __launch_bounds__(TPB) void fill2_k(const int* __restrict__ src_cm,
                                               const int* __restrict__ dst_cm,
                                               const int* __restrict__ src_am,
                                               const int* __restrict__ dst_am, int E,
                                               int* __restrict__ cur_m_cm,
                                               int* __restrict__ cur_m_am,
                                               int* __restrict__ cur_c,
                                               int* __restrict__ cur_a,
                                               int* __restrict__ pm_m_cm,
                                               int* __restrict__ pm_m_am,
                                               int* __restrict__ pm_c,
                                               int* __restrict__ pm_a) {
  int i = blockIdx.x * blockDim.x + threadIdx.x;
  if (i < E) {
    int s = src_cm[i], d = dst_cm[i];
    pm_m_cm[atomicAdd(&cur_m_cm[d], 1)] = s;
    pm_c[atomicAdd(&cur_c[s], 1)] = d;
  } else if (i < 2 * E) {
    int e = i - E;
    int s = src_am[e], d = dst_am[e];
    pm_m_am[atomicAdd(&cur_m_am[d], 1)] = s;
    pm_a[atomicAdd(&cur_a[s], 1)] = d;
  }
}

// ---------------- gather (f32 src 128-wide -> bf16 out), mean via rinv ----------------
__global__ __launch_bounds__(TPB) void gatherw_k(const float* __restrict__ x,
                                                 const int* __restrict__ rowptr,
                                                 const int* __restrict__ perm,
                                                 const float* __restrict__ rinv,
                                                 int N, ushort* __restrict__ out) {
  int nid = blockIdx.x * 8 + (threadIdx.x >> 5);
  if (nid >= N) return;
  int d = (threadIdx.x & 31) << 2;
  int s0 = rowptr[nid], s1 = rowptr[nid + 1];
  float4 acc = make_float4(0.f, 0.f, 0.f, 0.f);
  for (int j = s0; j < s1; ++j) {
    int src = perm[j];
    float4 v = *(const float4*)&x[((long long)src << 7) + d];
    acc.x += v.x; acc.y += v.y; acc.z += v.z; acc.w += v.w;
  }
  float r = rinv[nid];
  ushort4 o;
  o.x = f2bf(acc.x * r); o.y = f2bf(acc.y * r);
  o.z = f2bf(acc.z * r); o.w = f2bf(acc.w * r);
  *(ushort4*)&out[((long long)nid << 7) + d] = o;
}

// ---------------- dual-CSR gather: A[n] += r1*sum(S1 rows) + r2*sum(S2 rows) ----------
// bf16 sources 128-wide; single A read-modify-write per node
__global__ __launch_bounds__(TPB) void gather2_k(
    const ushort* __restrict__ s1, const ushort* __restrict__ s2,
    const int* __restrict__ rp1, const int* __restrict__ pm1, const float* __restrict__ ri1,
    const int* __restrict__ rp2, const int* __restrict__ pm2, const float* __restrict__ ri2,
    int N, float* __restrict__ out) {
  int nid = blockIdx.x * 8 + (threadIdx.x >> 5);
  if (nid >= N) return;
  int d = (threadIdx.x & 31) << 2;
  float4 a1 = make_float4(0.f, 0.f, 0.f, 0.f);
  for (int j = rp1[nid]; j < rp1[nid + 1]; ++j) {
    ushort4 v = *(const ushort4*)&s1[((long long)pm1[j] << 7) + d];
    a1.x += bf2f(v.x); a1.y += bf2f(v.y); a1.z += bf2f(v.z); a1.w += bf2f(v.w);
  }
  float4 a2 = make_float4(0.f, 0.f, 0.f, 0.f);
  for (int j = rp2[nid]; j < rp2[nid + 1]; ++j) {
    ushort4 v = *(const ushort4*)&s2[((long long)pm2[j] << 7) + d];
    a2.x += bf2f(v.x); a2.y += bf2f(v.y); a2.z += bf2f(v.z); a2.w += bf2f(v.w);
  }
  float r1 = ri1[nid], r2 = ri2[nid];
  float* p = &out[((long long)nid << 7) + d];
  float4 cur = *(float4*)p;
  cur.x = fmaf(a2.x, r2, fmaf(a1.x, r1, cur.x));
  cur.y = fmaf(a2.y, r2, fmaf(a1.y, r1, cur.y));
  cur.z = fmaf(a2.z, r2, fmaf(a1.z, r1, cur.z));
  cur.w = fmaf(a2.w, r2, fmaf(a1.w, r1, cur.w));
  *(float4*)p = cur;
}

// ---------------- MFMA multi-segment GEMM (+bias), N=128 ----------------
// out[row][:] = bias + sum_s f(X_s[row][:]) @ W_s ; W pre-transposed bf16 [128][K]
// xb0/xb1: runtime per-segment "X is bf16" flag. In-place safe (barrier before store).
#define BK 64
#define XPITCH 72
template <bool XRELU, bool OB16>
__global__ __launch_bounds__(TPB) void mfma_combine_k(
    const void* __restrict__ X0v, const ushort* __restrict__ WT0, int K0, int xb0,
    const void* __restrict__ X1v, const ushort* __restrict__ WT1, int K1, int xb1,
    int nseg, const float* __restrict__ bias, void* __restrict__ outv, int M) {
  __shared__ ushort Xs[128 * XPITCH];
  __shared__ ushort Ws[128 * XPITCH];
  const int t = threadIdx.x;
  const int lane = t & 63;
  const int wid = t >> 6;
  const int wm = (wid >> 1) << 6;
  const int wn = (wid & 1) << 6;
  const long long rbase = (long long)blockIdx.x * 128;

  f32x4 acc[4][4];
#pragma unroll
  for (int mi = 0; mi < 4; ++mi)
#pragma unroll
    for (int ni = 0; ni < 4; ++ni) acc[mi][ni] = (f32x4){0.f, 0.f, 0.f, 0.f};

  for (int s = 0; s < nseg; ++s) {
    const void* Xv = s ? X1v : X0v;
    const ushort* WT = s ? WT1 : WT0;
    const int K = s ? K1 : K0;
    const int xb = s ? xb1 : xb0;
    for (int k0 = 0; k0 < K; k0 += BK) {
      __syncthreads();
#pragma unroll
      for (int i = 0; i < 4; ++i) {
        int idx8 = t + i * TPB;
        int row = idx8 >> 3;
        int kb = (idx8 & 7) << 3;
        u16x8 xv;
        long long grow = rbase + row;
        if (grow < M) {
          if (xb) {
            xv = *(const u16x8*)((const ushort*)Xv + grow * K + k0 + kb);
            if (XRELU) {
#pragma unroll
              for (int j = 0; j < 8; ++j) xv[j] = (xv[j] & 0x8000u) ? (ushort)0 : xv[j];
            }
          } else {
            const float* xp = (const float*)Xv + grow * K + k0 + kb;
            float4 a = *(const float4*)xp;
            float4 b = *(const float4*)(xp + 4);
            if (XRELU) {
              a.x = fmaxf(a.x, 0.f); a.y = fmaxf(a.y, 0.f);
              a.z = fmaxf(a.z, 0.f); a.w = fmaxf(a.w, 0.f);
              b.x = fmaxf(b.x, 0.f); b.y = fmaxf(b.y, 0.f);
              b.z = fmaxf(b.z, 0.f); b.w = fmaxf(b.w, 0.f);
            }
            xv[0] = f2bf(a.x); xv[1] = f2bf(a.y); xv[2] = f2bf(a.z); xv[3] = f2bf(a.w);
            xv[4] = f2bf(b.x); xv[5] = f2bf(b.y); xv[6] = f2bf(b.z); xv[7] = f2bf(b.w);
          }
        } else {
#pragma unroll
          for (int j = 0; j < 8; ++j) xv[j] = 0;
        }
        *(u16x8*)&Xs[row * XPITCH + kb] = xv;
        *(u16x8*)&Ws[row * XPITCH + kb] = *(const u16x8*)(WT + (long long)row * K + k0 + kb);
      }
      __syncthreads();
#pragma unroll
      for (int kk = 0; kk < BK; kk += 32) {
        const int krow = kk + ((lane >> 4) << 3);
        bf16x8 af[4], bfr[4];
#pragma unroll
        for (int mi = 0; mi < 4; ++mi)
          af[mi] = *(const bf16x8*)&Xs[(wm + mi * 16 + (lane & 15)) * XPITCH + krow];
#pragma unroll
        for (int ni = 0; ni < 4; ++ni)
          bfr[ni] = *(const bf16x8*)&Ws[(wn + ni * 16 + (lane & 15)) * XPITCH + krow];
#pragma unroll
        for (int mi = 0; mi < 4; ++mi)
#pragma unroll
          for (int ni = 0; ni < 4; ++ni)
            acc[mi][ni] = __builtin_amdgcn_mfma_f32_16x16x32_bf16(af[mi], bfr[ni],
                                                                  acc[mi][ni], 0, 0, 0);
      }
    }
  }

  __syncthreads();  // in-place safety

  const int colbase = wn + (lane & 15);
  const int rsub = (lane >> 4) << 2;
#pragma unroll
  for (int ni = 0; ni < 4; ++ni) {
    int col = colbase + ni * 16;
    float bv = bias ? bias[col] : 0.f;
#pragma unroll
    for (int mi = 0; mi < 4; ++mi) {
      long long row0 = rbase + wm + mi * 16 + rsub;
#pragma unroll
      for (int j = 0; j < 4; ++j) {
        long long row = row0 + j;
        if (row < M) {
          float v = acc[mi][ni][j] + bv;
          if (OB16)
            ((ushort*)outv)[row * 128 + col] = f2bf(v);
          else
            ((float*)outv)[row * 128 + col] = v;
        }
      }
    }
  }
}

// ---------------- final linear: relu(X) (M x 128) @ (128 x 16) + b ----------------
__global__ __launch_bounds__(TPB) void final_k(const float* __restrict__ X,
                                               const float* __restrict__ W,
                                               const float* __restrict__ b,
                                               float* __restrict__ out, int M) {
  __shared__ float lw[128 * 16];
  __shared__ float lb[16];
  int t = threadIdx.x;
  for (int i = t; i < 2048; i += TPB) lw[i] = W[i];
  if (t < 16) lb[t] = b[t];
  __syncthreads();
  long long row = (long long)blockIdx.x * TPB + t;
  if (row >= M) return;
  float acc[16];
#pragma unroll
  for (int c = 0; c < 16; ++c) acc[c] = lb[c];
  const float* xr = &X[row * 128];
  for (int k = 0; k < 128; k += 4) {
    float4 xv = *(const float4*)&xr[k];
    xv.x = fmaxf(xv.x, 0.f); xv.y = fmaxf(xv.y, 0.f);
    xv.z = fmaxf(xv.z, 0.f); xv.w = fmaxf(xv.w, 0.f);
#pragma unroll
    for (int j = 0; j < 4; ++j) {
      float xsc = (j == 0) ? xv.x : (j == 1) ? xv.y : (j == 2) ? xv.z : xv.w;
#pragma unroll
      for (int c = 0; c < 16; ++c) acc[c] = fmaf(xsc, lw[(k + j) * 16 + c], acc[c]);
    }
  }
#pragma unroll
  for (int c = 0; c < 16; c += 4) {
    float4 o; o.x = acc[c]; o.y = acc[c + 1]; o.z = acc[c + 2]; o.w = acc[c + 3];
    *(float4*)&out[row * 16 + c] = o;
  }
}

// ---------------- launch ----------------
extern "C" void kernel_launch(void* const* d_in, const int* in_sizes, int n_in,
                              void* d_out, int out_size, void* d_ws, size_t ws_size,
                              hipStream_t stream) {
  const float* xm = (const float*)d_in[0];
  const float* xc = (const float*)d_in[1];
  const float* xa = (const float*)d_in[2];
  const int* src_cm = (const int*)d_in[3];
  const int* dst_cm = (const int*)d_in[4];
  const int* src_am = (const int*)d_in[5];
  const int* dst_am = (const int*)d_in[6];
  const float* Wl_cm_0 = (const float*)d_in[7];
  const float* Wr_cm_0 = (const float*)d_in[8];
  const float* b_cm_0  = (const float*)d_in[9];
  const float* Wl_am_0 = (const float*)d_in[10];
  const float* Wr_am_0 = (const float*)d_in[11];
  const float* b_am_0  = (const float*)d_in[12];
  const float* Wl_mc_0 = (const float*)d_in[13];
  const float* Wr_mc_0 = (const float*)d_in[14];
  const float* b_mc_0  = (const float*)d_in[15];
  const float* Wl_ma_0 = (const float*)d_in[16];
  const float* Wr_ma_0 = (const float*)d_in[17];
  const float* b_ma_0  = (const float*)d_in[18];
  const float* Wl_cm_1 = (const float*)d_in[19];
  const float* Wr_cm_1 = (const float*)d_in[20];
  const float* b_cm_1  = (const float*)d_in[21];
  const float* Wl_am_1 = (const float*)d_in[22];
  const float* Wr_am_1 = (const float*)d_in[23];
  const float* b_am_1  = (const float*)d_in[24];
  const float* lin_W   = (const float*)d_in[31];
  const float* lin_b   = (const float*)d_in[32];

  const int NM = in_sizes[0] / 128;
  const int NC = in_sizes[1] / 64;
  const int NA = in_sizes[2] / 64;
  const int E  = in_sizes[3];
  const int SMAX = (NC > NA) ? NC : NA;

  // ---- workspace layout (float units) ----
  float* base = (float*)d_ws;
  size_t o = 0;
  float* A = base + o; o += (size_t)NM * 128;             // movie features, f32
  float* S = base + o; o += (size_t)SMAX * 128;           // two bf16 halves S1h/S2h
  ushort* B = (ushort*)(base + o); o += (size_t)NC * 64;  // xc1 pre-relu, bf16
  ushort* C = (ushort*)(base + o); o += (size_t)NA * 64;  // xa1 pre-relu, bf16
  int* cnt_m_cm = (int*)(base + o); o += NM;              // cnt block (contiguous)
  int* cnt_m_am = (int*)(base + o); o += NM;
  int* cnt_c    = (int*)(base + o); o += NC;
  int* cnt_a    = (int*)(base + o); o += NA;
  float* rinv_m_cm = base + o; o += NM;                   // rinv block (same order)
  float* rinv_m_am = base + o; o += NM;
  float* rinv_c    = base + o; o += NC;
  float* rinv_a    = base + o; o += NA;
  int* rp_m_cm = (int*)(base + o); o += NM + 1;
  int* rp_m_am = (int*)(base + o); o += NM + 1;
  int* rp_c    = (int*)(base + o); o += NC + 1;
  int* rp_a    = (int*)(base + o); o += NA + 1;
  int* pm_m_cm = (int*)(base + o); o += E;
  int* pm_m_am = (int*)(base + o); o += E;
  int* pm_c    = (int*)(base + o); o += E;
  int* pm_a    = (int*)(base + o); o += E;
  int* bsum    = (int*)(base + o); o += 4096;             // 4 x 1024
  float* b0c  = base + o; o += 128;
  float* b1c  = base + o; o += 128;
  ushort* WT_r0   = (ushort*)(base + o); o += 8192;
  ushort* WT_r1   = (ushort*)(base + o); o += 8192;
  ushort* WT_mc0l = (ushort*)(base + o); o += 8192;
  ushort* WT_ma0l = (ushort*)(base + o); o += 8192;
  ushort* WT_cm1  = (ushort*)(base + o); o += 8192;
  ushort* WT_am1  = (ushort*)(base + o); o += 8192;
  ushort* WT_mc0r = (ushort*)(base + o); o += 4096;
  ushort* WT_ma0r = (ushort*)(base + o); o += 4096;
  ushort* WT_cm0  = (ushort*)(base + o); o += 4096;
  ushort* WT_am0  = (ushort*)(base + o); o += 4096;

  if (ws_size < o * sizeof(float)) return;  // diagnostic guard

  ushort* S1h = (ushort*)S;                      // SMAX x 128 bf16
  ushort* S2h = S1h + (size_t)SMAX * 128;        // SMAX x 128 bf16

  float* outf = (float*)d_out;
  const int g2E = (2 * E + TPB - 1) / TPB;
  const int nbm = (NM + TPB - 1) / TPB;
  const int nbc = (NC + TPB - 1) / TPB;
  const int nba = (NA + TPB - 1) / TPB;
  const int nodes_total = 2 * NM + NC + NA;

  // degree counts + reciprocal means
  hipMemsetAsync(cnt_m_cm, 0, sizeof(int) * (size_t)nodes_total, stream);
  count4_k<<<g2E, TPB, 0, stream>>>(src_cm, dst_cm, src_am, dst_am, E,
                                    cnt_m_cm, cnt_m_am, cnt_c, cnt_a);
  rinvall_k<<<(nodes_total + TPB - 1) / TPB, TPB, 0, stream>>>(cnt_m_cm, rinv_m_cm,
                                                               2 * NM, nodes_total);

  // averaged biases + bf16-transposed weights
  avg2_k<<<1, TPB, 0, stream>>>(b_cm_0, b_am_0, b0c, 128);
  avg2_k<<<1, TPB, 0, stream>>>(b_cm_1, b_am_1, b1c, 128);
  wprep_k<<<64, TPB, 0, stream>>>(Wr_cm_0, Wr_am_0, 128, WT_r0);
  wprep_k<<<64, TPB, 0, stream>>>(Wr_cm_1, Wr_am_1, 128, WT_r1);
  wprep_k<<<64, TPB, 0, stream>>>(Wl_mc_0, nullptr, 128, WT_mc0l);
  wprep_k<<<64, TPB, 0, stream>>>(Wl_ma_0, nullptr, 128, WT_ma0l);
  wprep_k<<<64, TPB, 0, stream>>>(Wl_cm_1, nullptr, 128, WT_cm1);
  wprep_k<<<64, TPB, 0, stream>>>(Wl_am_1, nullptr, 128, WT_am1);
  wprep_k<<<32, TPB, 0, stream>>>(Wr_mc_0, nullptr, 64, WT_mc0r);
  wprep_k<<<32, TPB, 0, stream>>>(Wr_ma_0, nullptr, 64, WT_ma0r);
  wprep_k<<<32, TPB, 0, stream>>>(Wl_cm_0, nullptr, 64, WT_cm0);
  wprep_k<<<32, TPB, 0, stream>>>(Wl_am_0, nullptr, 64, WT_am0);

  // CSR builds: 4 dispatches total (order: m_cm, m_am, c, a)
  blocksum_all_k<<<2 * nbm + nbc + nba, TPB, 0, stream>>>(
      cnt_m_cm, NM, cnt_m_am, NM, cnt_c, NC, cnt_a, NA, bsum);
  scan_all_k<<<4, TPB, 0, stream>>>(bsum, NM, NM, NC, NA);
  finalize_all_k<<<2 * nbm + nbc + nba, TPB, 0, stream>>>(
      cnt_m_cm, NM, rp_m_cm, cnt_m_am, NM, rp_m_am,
      cnt_c, NC, rp_c, cnt_a, NA, rp_a, bsum);
  fill2_k<<<g2E, TPB, 0, stream>>>(src_cm, dst_cm, src_am, dst_am, E,
                                   cnt_m_cm, cnt_m_am, cnt_c, cnt_a,
                                   pm_m_cm, pm_m_am, pm_c, pm_a);

  const int gM = (NM + 127) / 128;
  const int gC = (NC + 127) / 128;
  const int gA = (NA + 127) / 128;
  const int gnM = (NM + 7) / 8;

  // ---- layer 0: crew & cast (gather movie means -> bf16, then 2-seg combine) ----
  gatherw_k<<<(NC + 7) / 8, TPB, 0, stream>>>(xm, rp_c, pm_c, rinv_c, NC, S1h);
  gatherw_k<<<(NA + 7) / 8, TPB, 0, stream>>>(xm, rp_a, pm_a, rinv_a, NA, S2h);
  mfma_combine_k<false, true><<<gC, TPB, 0, stream>>>(
      S1h, WT_mc0l, 128, 1, xc, WT_mc0r, 64, 0, 2, b_mc_0, B, NC);
  mfma_combine_k<false, true><<<gA, TPB, 0, stream>>>(
      S2h, WT_ma0l, 128, 1, xa, WT_ma0r, 64, 0, 2, b_ma_0, C, NA);

  // ---- layer 0: movies (GEMM-first; dual-gather transformed sources into A) ----
  mfma_combine_k<false, false><<<gM, TPB, 0, stream>>>(
      xm, WT_r0, 128, 0, nullptr, nullptr, 0, 0, 1, b0c, A, NM);       // A = xm@Wr0+b
  mfma_combine_k<false, true><<<gC, TPB, 0, stream>>>(
      xc, WT_cm0, 64, 0, nullptr, nullptr, 0, 0, 1, nullptr, S1h, NC); // S1h = xc@Wl_cm0
  mfma_combine_k<false, true><<<gA, TPB, 0, stream>>>(
      xa, WT_am0, 64, 0, nullptr, nullptr, 0, 0, 1, nullptr, S2h, NA); // S2h = xa@Wl_am0
  gather2_k<<<gnM, TPB, 0, stream>>>(S1h, S2h, rp_m_cm, pm_m_cm, rinv_m_cm,
                                     rp_m_am, pm_m_am, rinv_m_am, NM, A);
  // A = xm1 pre-relu

  // ---- layer 1: movies only ----
  mfma_combine_k<true, false><<<gM, TPB, 0, stream>>>(
      A, WT_r1, 128, 0, nullptr, nullptr, 0, 0, 1, b1c, A, NM);        // in-place
  mfma_combine_k<true, true><<<gC, TPB, 0, stream>>>(
      B, WT_cm1, 128, 1, nullptr, nullptr, 0, 0, 1, nullptr, S1h, NC); // relu(B)@Wl_cm1
  mfma_combine_k<true, true><<<gA, TPB, 0, stream>>>(
      C, WT_am1, 128, 1, nullptr, nullptr, 0, 0, 1, nullptr, S2h, NA); // relu(C)@Wl_am1
  gather2_k<<<gnM, TPB, 0, stream>>>(S1h, S2h, rp_m_cm, pm_m_cm, rinv_m_cm,
                                     rp_m_am, pm_m_am, rinv_m_am, NM, A);
  // A = xm2 pre-relu

  // ---- final linear ----
  final_k<<<(NM + TPB - 1) / TPB, TPB, 0, stream>>>(A, lin_W, lin_b, outf, NM);
}

// Round 8
// 797.502 us; speedup vs baseline: 9.1747x; 1.3671x over previous
//
#include <hip/hip_runtime.h>

#define TPB 256
typedef unsigned int uint;
typedef unsigned short ushort;
typedef long long ll;
typedef __attribute__((ext_vector_type(8))) short bf16x8;
typedef __attribute__((ext_vector_type(8))) ushort u16x8;
typedef __attribute__((ext_vector_type(4))) float f32x4;

__device__ __forceinline__ float bf2f(ushort h) {
  return __uint_as_float(((uint)h) << 16);
}
__device__ __forceinline__ ushort f2bf(float f) {
  uint u = __float_as_uint(f);
  u += 0x7fffu + ((u >> 16) & 1u);
  return (ushort)(u >> 16);
}

// ---------------- rank pass: counts + per-edge local rank in ONE atomic pass ---------
__global__ __launch_bounds__(TPB) void rank_k(const int* __restrict__ src_cm,
                                              const int* __restrict__ dst_cm,
                                              const int* __restrict__ src_am,
                                              const int* __restrict__ dst_am, int E,
                                              int* __restrict__ cnt_m_cm,
                                              int* __restrict__ cnt_m_am,
                                              int* __restrict__ cnt_c,
                                              int* __restrict__ cnt_a,
                                              int* __restrict__ rk_m_cm,
                                              int* __restrict__ rk_c,
                                              int* __restrict__ rk_m_am,
                                              int* __restrict__ rk_a) {
  int i = blockIdx.x * blockDim.x + threadIdx.x;
  if (i < E) {
    rk_m_cm[i] = atomicAdd(&cnt_m_cm[dst_cm[i]], 1);
    rk_c[i]    = atomicAdd(&cnt_c[src_cm[i]], 1);
  } else if (i < 2 * E) {
    int e = i - E;
    rk_m_am[e] = atomicAdd(&cnt_m_am[dst_am[e]], 1);
    rk_a[e]    = atomicAdd(&cnt_a[src_am[e]], 1);
  }
}

// cnt block and rinv block contiguous, same order: [m_cm NM][m_am NM][c NC][a NA]
__global__ __launch_bounds__(TPB) void rinvall_k(const int* __restrict__ cnt,
                                                 float* __restrict__ rinv,
                                                 int nm2, int total) {
  int i = blockIdx.x * blockDim.x + threadIdx.x;
  if (i < total) {
    float scale = (i < nm2) ? 0.5f : 1.0f;
    rinv[i] = scale / fmaxf((float)cnt[i], 1.0f);
  }
}

// ---------------- one-dispatch prep: 10 weight transposes + 2 bias averages ----------
struct PJobs {
  const float* a[10];
  const float* bavg[10];
  ushort* out[10];
  const float* ba[2];
  const float* bb[2];
  float* bo[2];
};

__global__ __launch_bounds__(TPB) void prep_k(PJobs J) {
  int b = blockIdx.x;
  int t = threadIdx.x;
  if (b == 512) {  // biases
    if (t < 128) J.bo[0][t] = 0.5f * (J.ba[0][t] + J.bb[0][t]);
    else if (t < 256) J.bo[1][t - 128] = 0.5f * (J.ba[1][t - 128] + J.bb[1][t - 128]);
    return;
  }
  int job, idx, K;
  if (b < 384) { job = b >> 6; idx = ((b & 63) << 8) | t; K = 128; }
  else { int bb = b - 384; job = 6 + (bb >> 5); idx = ((bb & 31) << 8) | t; K = 64; }
  int col = idx / K, k = idx - col * K;
  float v = J.a[job][k * 128 + col];
  if (J.bavg[job]) v = 0.5f * (v + J.bavg[job][k * 128 + col]);
  J.out[job][idx] = f2bf(v);
}

// ---------------- CSR build (all 4 relations per dispatch) ----------------
__device__ __forceinline__ void rel_map(int b, int nb0, int nb1, int nb2, int nb3,
                                        int& r, int& lb) {
  if (b < nb0) { r = 0; lb = b; }
  else if (b < nb0 + nb1) { r = 1; lb = b - nb0; }
  else if (b < nb0 + nb1 + nb2) { r = 2; lb = b - nb0 - nb1; }
  else { r = 3; lb = b - nb0 - nb1 - nb2; }
}

__global__ __launch_bounds__(TPB) void blocksum_all_k(
    const int* __restrict__ c0, int n0, const int* __restrict__ c1, int n1,
    const int* __restrict__ c2, int n2, const int* __restrict__ c3, int n3,
    int* __restrict__ bsum) {
  __shared__ int lds[TPB];
  int nb0 = (n0 + TPB - 1) / TPB, nb1 = (n1 + TPB - 1) / TPB;
  int nb2 = (n2 + TPB - 1) / TPB, nb3 = (n3 + TPB - 1) / TPB;
  int r, lb;
  rel_map(blockIdx.x, nb0, nb1, nb2, nb3, r, lb);
  const int* cnt = (r == 0) ? c0 : (r == 1) ? c1 : (r == 2) ? c2 : c3;
  int n = (r == 0) ? n0 : (r == 1) ? n1 : (r == 2) ? n2 : n3;
  int t = threadIdx.x;
  int i = lb * TPB + t;
  lds[t] = (i < n) ? cnt[i] : 0;
  __syncthreads();
  for (int off = 128; off > 0; off >>= 1) {
    if (t < off) lds[t] += lds[t + off];
    __syncthreads();
  }
  if (t == 0) bsum[r * 1024 + lb] = lds[0];
}

__global__ __launch_bounds__(TPB) void scan_all_k(int* __restrict__ bsum,
                                                  int n0, int n1, int n2, int n3) {
  __shared__ int lds[TPB];
  int r = blockIdx.x;
  int n = (r == 0) ? n0 : (r == 1) ? n1 : (r == 2) ? n2 : n3;
  int nb = (n + TPB - 1) / TPB;
  int* bs = bsum + r * 1024;
  int t = threadIdx.x;
  int offset = 0;
  for (int base = 0; base < nb; base += TPB) {
    int v = (base + t < nb) ? bs[base + t] : 0;
    lds[t] = v;
    __syncthreads();
    for (int off = 1; off < TPB; off <<= 1) {
      int add = (t >= off) ? lds[t - off] : 0;
      __syncthreads();
      lds[t] += add;
      __syncthreads();
    }
    int incl = lds[t];
    if (base + t < nb) bs[base + t] = offset + incl - v;
    int tot = lds[TPB - 1];
    __syncthreads();
    offset += tot;
  }
}

__global__ __launch_bounds__(TPB) void finalize_all_k(
    const int* __restrict__ c0, int n0, int* __restrict__ rp0,
    const int* __restrict__ c1, int n1, int* __restrict__ rp1,
    const int* __restrict__ c2, int n2, int* __restrict__ rp2,
    const int* __restrict__ c3, int n3, int* __restrict__ rp3,
    const int* __restrict__ bsum) {
  __shared__ int lds[TPB];
  int nb0 = (n0 + TPB - 1) / TPB, nb1 = (n1 + TPB - 1) / TPB;
  int nb2 = (n2 + TPB - 1) / TPB, nb3 = (n3 + TPB - 1) / TPB;
  int r, lb;
  rel_map(blockIdx.x, nb0, nb1, nb2, nb3, r, lb);
  const int* cnt = (r == 0) ? c0 : (r == 1) ? c1 : (r == 2) ? c2 : c3;
  int* rowptr = (r == 0) ? rp0 : (r == 1) ? rp1 : (r == 2) ? rp2 : rp3;
  int n = (r == 0) ? n0 : (r == 1) ? n1 : (r == 2) ? n2 : n3;
  int t = threadIdx.x;
  int i = lb * TPB + t;
  int v = (i < n) ? cnt[i] : 0;
  lds[t] = v;
  __syncthreads();
  for (int off = 1; off < TPB; off <<= 1) {
    int add = (t >= off) ? lds[t - off] : 0;
    __syncthreads();
    lds[t] += add;
    __syncthreads();
  }
  int ex = lds[t] - v + bsum[r * 1024 + lb];
  if (i < n) {
    rowptr[i] = ex;
    if (i == n - 1) rowptr[n] = ex + v;
  }
}

// fill via precomputed ranks: NO atomics
__global__ __launch_bounds__(TPB) void fillr_k(const int* __restrict__ src_cm,
                                               const int* __restrict__ dst_cm,
                                               const int* __restrict__ src_am,
                                               const int* __restrict__ dst_am, int E,
                                               const int* __restrict__ rp_m_cm,
                                               const int* __restrict__ rp_m_am,
                                               const int* __restrict__ rp_c,
                                               const int* __restrict__ rp_a,
                                               const int* __restrict__ rk_m_cm,
                                               const int* __restrict__ rk_c,
                                               const int* __restrict__ rk_m_am,
                                               const int* __restrict__ rk_a,
                                               int* __restrict__ pm_m_cm,
                                               int* __restrict__ pm_m_am,
                                               int* __restrict__ pm_c,
                                               int* __restrict__ pm_a) {
  int i = blockIdx.x * blockDim.x + threadIdx.x;
  if (i < E) {
    int s = src_cm[i], d = dst_cm[i];
    pm_m_cm[rp_m_cm[d] + rk_m_cm[i]] = s;
    pm_c[rp_c[s] + rk_c[i]] = d;
  } else if (i < 2 * E) {
    int e = i - E;
    int s = src_am[e], d = dst_am[e];
    pm_m_am[rp_m_am[d] + rk_m_am[e]] = s;
    pm_a[rp_a[s] + rk_a[e]] = d;
  }
}

// ---------------- merged crew+cast gather (f32 xm -> bf16 means) ----------------
__global__ __launch_bounds__(TPB) void gatherw2_k(
    const float* __restrict__ xm,
    const int* __restrict__ rp1, const int* __restrict__ pm1,
    const float* __restrict__ ri1, int N1, ushort* __restrict__ o1,
    const int* __restrict__ rp2, const int* __restrict__ pm2,
    const float* __restrict__ ri2, int N2, ushort* __restrict__ o2, int g1) {
  int b = blockIdx.x;
  const int* rowptr; const int* perm; const float* rinv; int N; ushort* out;
  int lb;
  if (b < g1) { rowptr = rp1; perm = pm1; rinv = ri1; N = N1; out = o1; lb = b; }
  else { rowptr = rp2; perm = pm2; rinv = ri2; N = N2; out = o2; lb = b - g1; }
  int nid = lb * 8 + (threadIdx.x >> 5);
  if (nid >= N) return;
  int d = (threadIdx.x & 31) << 2;
  int s0 = rowptr[nid], s1 = rowptr[nid + 1];
  float4 acc = make_float4(0.f, 0.f, 0.f, 0.f);
  for (int j = s0; j < s1; ++j) {
    float4 v = *(const float4*)&xm[((ll)perm[j] << 7) + d];
    acc.x += v.x; acc.y += v.y; acc.z += v.z; acc.w += v.w;
  }
  float r = rinv[nid];
  ushort4 o;
  o.x = f2bf(acc.x * r); o.y = f2bf(acc.y * r);
  o.z = f2bf(acc.z * r); o.w = f2bf(acc.w * r);
  *(ushort4*)&out[((ll)nid << 7) + d] = o;
}

// ---------------- dual-CSR gather into bf16 A (single RMW) ----------------
__global__ __launch_bounds__(TPB) void gather2_k(
    const ushort* __restrict__ s1, const ushort* __restrict__ s2,
    const int* __restrict__ rp1, const int* __restrict__ pm1, const float* __restrict__ ri1,
    const int* __restrict__ rp2, const int* __restrict__ pm2, const float* __restrict__ ri2,
    int N, ushort* __restrict__ out) {
  int nid = blockIdx.x * 8 + (threadIdx.x >> 5);
  if (nid >= N) return;
  int d = (threadIdx.x & 31) << 2;
  float4 a1 = make_float4(0.f, 0.f, 0.f, 0.f);
  for (int j = rp1[nid]; j < rp1[nid + 1]; ++j) {
    ushort4 v = *(const ushort4*)&s1[((ll)pm1[j] << 7) + d];
    a1.x += bf2f(v.x); a1.y += bf2f(v.y); a1.z += bf2f(v.z); a1.w += bf2f(v.w);
  }
  float4 a2 = make_float4(0.f, 0.f, 0.f, 0.f);
  for (int j = rp2[nid]; j < rp2[nid + 1]; ++j) {
    ushort4 v = *(const ushort4*)&s2[((ll)pm2[j] << 7) + d];
    a2.x += bf2f(v.x); a2.y += bf2f(v.y); a2.z += bf2f(v.z); a2.w += bf2f(v.w);
  }
  float r1 = ri1[nid], r2 = ri2[nid];
  ushort* p = &out[((ll)nid << 7) + d];
  ushort4 cur = *(ushort4*)p;
  ushort4 o;
  o.x = f2bf(bf2f(cur.x) + a1.x * r1 + a2.x * r2);
  o.y = f2bf(bf2f(cur.y) + a1.y * r1 + a2.y * r2);
  o.z = f2bf(bf2f(cur.z) + a1.z * r1 + a2.z * r2);
  o.w = f2bf(bf2f(cur.w) + a1.w * r1 + a2.w * r2);
  *(ushort4*)p = o;
}

// ---------------- MFMA multi-segment GEMM (+bias), N=128, dual-problem --------------
// out[row][:] = bias + sum_s f(X_s[row][:]) @ W_s ; W pre-transposed bf16 [128][K]
// Two independent problems per dispatch (block ranges). In-place safe (barrier).
#define BK 64
#define XPITCH 72
struct CArgs {
  const void* X0; const ushort* WT0; int K0; int xb0;
  const void* X1; const ushort* WT1; int K1; int xb1;
  int nseg; const float* bias; void* out; int M; int nblk;
};

template <bool XRELU, bool OB16>
__global__ __launch_bounds__(TPB) void mfma2_k(CArgs a0, CArgs a1) {
  const bool first = (int)blockIdx.x < a0.nblk;
  const CArgs& a = first ? a0 : a1;
  const int blk = first ? blockIdx.x : blockIdx.x - a0.nblk;

  __shared__ ushort Xs[128 * XPITCH];
  __shared__ ushort Ws[128 * XPITCH];
  const int t = threadIdx.x;
  const int lane = t & 63;
  const int wid = t >> 6;
  const int wm = (wid >> 1) << 6;
  const int wn = (wid & 1) << 6;
  const ll rbase = (ll)blk * 128;
  const int M = a.M;

  f32x4 acc[4][4];
#pragma unroll
  for (int mi = 0; mi < 4; ++mi)
#pragma unroll
    for (int ni = 0; ni < 4; ++ni) acc[mi][ni] = (f32x4){0.f, 0.f, 0.f, 0.f};

  for (int s = 0; s < a.nseg; ++s) {
    const void* Xv = s ? a.X1 : a.X0;
    const ushort* WT = s ? a.WT1 : a.WT0;
    const int K = s ? a.K1 : a.K0;
    const int xb = s ? a.xb1 : a.xb0;
    for (int k0 = 0; k0 < K; k0 += BK) {
      __syncthreads();
#pragma unroll
      for (int i = 0; i < 4; ++i) {
        int idx8 = t + i * TPB;
        int row = idx8 >> 3;
        int kb = (idx8 & 7) << 3;
        u16x8 xv;
        ll grow = rbase + row;
        if (grow < M) {
          if (xb) {
            xv = *(const u16x8*)((const ushort*)Xv + grow * K + k0 + kb);
            if (XRELU) {
#pragma unroll
              for (int j = 0; j < 8; ++j) xv[j] = (xv[j] & 0x8000u) ? (ushort)0 : xv[j];
            }
          } else {
            const float* xp = (const float*)Xv + grow * K + k0 + kb;
            float4 va = *(const float4*)xp;
            float4 vb = *(const float4*)(xp + 4);
            if (XRELU) {
              va.x = fmaxf(va.x, 0.f); va.y = fmaxf(va.y, 0.f);
              va.z = fmaxf(va.z, 0.f); va.w = fmaxf(va.w, 0.f);
              vb.x = fmaxf(vb.x, 0.f); vb.y = fmaxf(vb.y, 0.f);
              vb.z = fmaxf(vb.z, 0.f); vb.w = fmaxf(vb.w, 0.f);
            }
            xv[0] = f2bf(va.x); xv[1] = f2bf(va.y); xv[2] = f2bf(va.z); xv[3] = f2bf(va.w);
            xv[4] = f2bf(vb.x); xv[5] = f2bf(vb.y); xv[6] = f2bf(vb.z); xv[7] = f2bf(vb.w);
          }
        } else {
#pragma unroll
          for (int j = 0; j < 8; ++j) xv[j] = 0;
        }
        *(u16x8*)&Xs[row * XPITCH + kb] = xv;
        *(u16x8*)&Ws[row * XPITCH + kb] = *(const u16x8*)(WT + (ll)row * K + k0 + kb);
      }
      __syncthreads();
#pragma unroll
      for (int kk = 0; kk < BK; kk += 32) {
        const int krow = kk + ((lane >> 4) << 3);
        bf16x8 af[4], bfr[4];
#pragma unroll
        for (int mi = 0; mi < 4; ++mi)
          af[mi] = *(const bf16x8*)&Xs[(wm + mi * 16 + (lane & 15)) * XPITCH + krow];
#pragma unroll
        for (int ni = 0; ni < 4; ++ni)
          bfr[ni] = *(const bf16x8*)&Ws[(wn + ni * 16 + (lane & 15)) * XPITCH + krow];
#pragma unroll
        for (int mi = 0; mi < 4; ++mi)
#pragma unroll
          for (int ni = 0; ni < 4; ++ni)
            acc[mi][ni] = __builtin_amdgcn_mfma_f32_16x16x32_bf16(af[mi], bfr[ni],
                                                                  acc[mi][ni], 0, 0, 0);
      }
    }
  }

  __syncthreads();  // in-place safety

  const int colbase = wn + (lane & 15);
  const int rsub = (lane >> 4) << 2;
#pragma unroll
  for (int ni = 0; ni < 4; ++ni) {
    int col = colbase + ni * 16;
    float bv = a.bias ? a.bias[col] : 0.f;
#pragma unroll
    for (int mi = 0; mi < 4; ++mi) {
      ll row0 = rbase + wm + mi * 16 + rsub;
#pragma unroll
      for (int j = 0; j < 4; ++j) {
        ll row = row0 + j;
        if (row < M) {
          float v = acc[mi][ni][j] + bv;
          if (OB16)
            ((ushort*)a.out)[row * 128 + col] = f2bf(v);
          else
            ((float*)a.out)[row * 128 + col] = v;
        }
      }
    }
  }
}

// ---------------- final linear: relu(X bf16) (M x 128) @ (128 x 16) + b -------------
__global__ __launch_bounds__(TPB) void final_k(const ushort* __restrict__ X,
                                               const float* __restrict__ W,
                                               const float* __restrict__ b,
                                               float* __restrict__ out, int M) {
  __shared__ float lw[128 * 16];
  __shared__ float lb[16];
  int t = threadIdx.x;
  for (int i = t; i < 2048; i += TPB) lw[i] = W[i];
  if (t < 16) lb[t] = b[t];
  __syncthreads();
  ll row = (ll)blockIdx.x * TPB + t;
  if (row >= M) return;
  float acc[16];
#pragma unroll
  for (int c = 0; c < 16; ++c) acc[c] = lb[c];
  const ushort* xr = &X[row * 128];
  for (int k = 0; k < 128; k += 8) {
    u16x8 xv = *(const u16x8*)&xr[k];
#pragma unroll
    for (int j = 0; j < 8; ++j) {
      float xs = fmaxf(bf2f(xv[j]), 0.f);
#pragma unroll
      for (int c = 0; c < 16; ++c) acc[c] = fmaf(xs, lw[(k + j) * 16 + c], acc[c]);
    }
  }
#pragma unroll
  for (int c = 0; c < 16; c += 4) {
    float4 o; o.x = acc[c]; o.y = acc[c + 1]; o.z = acc[c + 2]; o.w = acc[c + 3];
    *(float4*)&out[row * 16 + c] = o;
  }
}

// ---------------- launch ----------------
extern "C" void kernel_launch(void* const* d_in, const int* in_sizes, int n_in,
                              void* d_out, int out_size, void* d_ws, size_t ws_size,
                              hipStream_t stream) {
  const float* xm = (const float*)d_in[0];
  const float* xc = (const float*)d_in[1];
  const float* xa = (const float*)d_in[2];
  const int* src_cm = (const int*)d_in[3];
  const int* dst_cm = (const int*)d_in[4];
  const int* src_am = (const int*)d_in[5];
  const int* dst_am = (const int*)d_in[6];
  const float* Wl_cm_0 = (const float*)d_in[7];
  const float* Wr_cm_0 = (const float*)d_in[8];
  const float* b_cm_0  = (const float*)d_in[9];
  const float* Wl_am_0 = (const float*)d_in[10];
  const float* Wr_am_0 = (const float*)d_in[11];
  const float* b_am_0  = (const float*)d_in[12];
  const float* Wl_mc_0 = (const float*)d_in[13];
  const float* Wr_mc_0 = (const float*)d_in[14];
  const float* b_mc_0  = (const float*)d_in[15];
  const float* Wl_ma_0 = (const float*)d_in[16];
  const float* Wr_ma_0 = (const float*)d_in[17];
  const float* b_ma_0  = (const float*)d_in[18];
  const float* Wl_cm_1 = (const float*)d_in[19];
  const float* Wr_cm_1 = (const float*)d_in[20];
  const float* b_cm_1  = (const float*)d_in[21];
  const float* Wl_am_1 = (const float*)d_in[22];
  const float* Wr_am_1 = (const float*)d_in[23];
  const float* b_am_1  = (const float*)d_in[24];
  const float* lin_W   = (const float*)d_in[31];
  const float* lin_b   = (const float*)d_in[32];

  const int NM = in_sizes[0] / 128;
  const int NC = in_sizes[1] / 64;
  const int NA = in_sizes[2] / 64;
  const int E  = in_sizes[3];
  const int SMAX = (NC > NA) ? NC : NA;

  // ---- workspace layout (float units) ----
  float* base = (float*)d_ws;
  size_t o = 0;
  ushort* A = (ushort*)(base + o); o += (size_t)NM * 64;  // movie features bf16
  float* S = base + o; o += (size_t)SMAX * 128;           // S1h/S2h bf16 halves; ranks early
  ushort* B = (ushort*)(base + o); o += (size_t)NC * 64;  // xc1 pre-relu, bf16
  ushort* C = (ushort*)(base + o); o += (size_t)NA * 64;  // xa1 pre-relu, bf16
  int* cnt_m_cm = (int*)(base + o); o += NM;              // contiguous cnt block
  int* cnt_m_am = (int*)(base + o); o += NM;
  int* cnt_c    = (int*)(base + o); o += NC;
  int* cnt_a    = (int*)(base + o); o += NA;
  float* rinv_m_cm = base + o; o += NM;                   // rinv block (same order)
  float* rinv_m_am = base + o; o += NM;
  float* rinv_c    = base + o; o += NC;
  float* rinv_a    = base + o; o += NA;
  int* rp_m_cm = (int*)(base + o); o += NM + 1;
  int* rp_m_am = (int*)(base + o); o += NM + 1;
  int* rp_c    = (int*)(base + o); o += NC + 1;
  int* rp_a    = (int*)(base + o); o += NA + 1;
  int* pm_m_cm = (int*)(base + o); o += E;
  int* pm_m_am = (int*)(base + o); o += E;
  int* pm_c    = (int*)(base + o); o += E;
  int* pm_a    = (int*)(base + o); o += E;
  int* bsum    = (int*)(base + o); o += 4096;
  float* b0c  = base + o; o += 128;
  float* b1c  = base + o; o += 128;
  ushort* WT_r0   = (ushort*)(base + o); o += 8192;
  ushort* WT_r1   = (ushort*)(base + o); o += 8192;
  ushort* WT_mc0l = (ushort*)(base + o); o += 8192;
  ushort* WT_ma0l = (ushort*)(base + o); o += 8192;
  ushort* WT_cm1  = (ushort*)(base + o); o += 8192;
  ushort* WT_am1  = (ushort*)(base + o); o += 8192;
  ushort* WT_mc0r = (ushort*)(base + o); o += 4096;
  ushort* WT_ma0r = (ushort*)(base + o); o += 4096;
  ushort* WT_cm0  = (ushort*)(base + o); o += 4096;
  ushort* WT_am0  = (ushort*)(base + o); o += 4096;

  if (ws_size < o * sizeof(float)) return;  // diagnostic guard

  // ranks overlay S (S is written only after fillr completes)
  int* rk_m_cm = (int*)S;
  int* rk_c    = rk_m_cm + E;
  int* rk_m_am = rk_m_cm + 2 * E;
  int* rk_a    = rk_m_cm + 3 * E;
  ushort* S1h = (ushort*)S;
  ushort* S2h = S1h + (size_t)SMAX * 128;

  float* outf = (float*)d_out;
  const int g2E = (2 * E + TPB - 1) / TPB;
  const int nbm = (NM + TPB - 1) / TPB;
  const int nbc = (NC + TPB - 1) / TPB;
  const int nba = (NA + TPB - 1) / TPB;
  const int nbtot = 2 * nbm + nbc + nba;
  const int nodes_total = 2 * NM + NC + NA;

  // 1) counts + ranks in one atomic pass
  hipMemsetAsync(cnt_m_cm, 0, sizeof(int) * (size_t)nodes_total, stream);
  rank_k<<<g2E, TPB, 0, stream>>>(src_cm, dst_cm, src_am, dst_am, E,
                                  cnt_m_cm, cnt_m_am, cnt_c, cnt_a,
                                  rk_m_cm, rk_c, rk_m_am, rk_a);
  rinvall_k<<<(nodes_total + TPB - 1) / TPB, TPB, 0, stream>>>(cnt_m_cm, rinv_m_cm,
                                                               2 * NM, nodes_total);

  // 2) single-dispatch weight/bias prep
  PJobs J;
  J.a[0] = Wr_cm_0; J.bavg[0] = Wr_am_0; J.out[0] = WT_r0;
  J.a[1] = Wr_cm_1; J.bavg[1] = Wr_am_1; J.out[1] = WT_r1;
  J.a[2] = Wl_mc_0; J.bavg[2] = nullptr; J.out[2] = WT_mc0l;
  J.a[3] = Wl_ma_0; J.bavg[3] = nullptr; J.out[3] = WT_ma0l;
  J.a[4] = Wl_cm_1; J.bavg[4] = nullptr; J.out[4] = WT_cm1;
  J.a[5] = Wl_am_1; J.bavg[5] = nullptr; J.out[5] = WT_am1;
  J.a[6] = Wr_mc_0; J.bavg[6] = nullptr; J.out[6] = WT_mc0r;
  J.a[7] = Wr_ma_0; J.bavg[7] = nullptr; J.out[7] = WT_ma0r;
  J.a[8] = Wl_cm_0; J.bavg[8] = nullptr; J.out[8] = WT_cm0;
  J.a[9] = Wl_am_0; J.bavg[9] = nullptr; J.out[9] = WT_am0;
  J.ba[0] = b_cm_0; J.bb[0] = b_am_0; J.bo[0] = b0c;
  J.ba[1] = b_cm_1; J.bb[1] = b_am_1; J.bo[1] = b1c;
  prep_k<<<513, TPB, 0, stream>>>(J);

  // 3) rowptrs + atomic-free fill
  blocksum_all_k<<<nbtot, TPB, 0, stream>>>(cnt_m_cm, NM, cnt_m_am, NM,
                                            cnt_c, NC, cnt_a, NA, bsum);
  scan_all_k<<<4, TPB, 0, stream>>>(bsum, NM, NM, NC, NA);
  finalize_all_k<<<nbtot, TPB, 0, stream>>>(cnt_m_cm, NM, rp_m_cm, cnt_m_am, NM, rp_m_am,
                                            cnt_c, NC, rp_c, cnt_a, NA, rp_a, bsum);
  fillr_k<<<g2E, TPB, 0, stream>>>(src_cm, dst_cm, src_am, dst_am, E,
                                   rp_m_cm, rp_m_am, rp_c, rp_a,
                                   rk_m_cm, rk_c, rk_m_am, rk_a,
                                   pm_m_cm, pm_m_am, pm_c, pm_a);

  const int gM = (NM + 127) / 128;
  const int gC = (NC + 127) / 128;
  const int gA = (NA + 127) / 128;
  const int gnM = (NM + 7) / 8;
  const int gwc = (NC + 7) / 8;
  const int gwa = (NA + 7) / 8;
  CArgs Z = {};  // zeroed dummy (nblk=0)

  // ---- layer 0: crew & cast movie-mean gathers (merged) ----
  gatherw2_k<<<gwc + gwa, TPB, 0, stream>>>(xm, rp_c, pm_c, rinv_c, NC, S1h,
                                            rp_a, pm_a, rinv_a, NA, S2h, gwc);
  // crew/cast L0 combines (merged): B = [S1h@Wl_mc0 + xc@Wr_mc0 + b], same for C
  {
    CArgs ac = {S1h, WT_mc0l, 128, 1, xc, WT_mc0r, 64, 0, 2, b_mc_0, B, NC, gC};
    CArgs aa = {S2h, WT_ma0l, 128, 1, xa, WT_ma0r, 64, 0, 2, b_ma_0, C, NA, gA};
    mfma2_k<false, true><<<gC + gA, TPB, 0, stream>>>(ac, aa);
  }

  // ---- layer 0: movies (GEMM-first) ----
  {
    CArgs am = {xm, WT_r0, 128, 0, nullptr, nullptr, 0, 0, 1, b0c, A, NM, gM};
    mfma2_k<false, true><<<gM, TPB, 0, stream>>>(am, Z);  // A = bf16(xm@Wr0 + b0c)
  }
  {
    CArgs ac = {xc, WT_cm0, 64, 0, nullptr, nullptr, 0, 0, 1, nullptr, S1h, NC, gC};
    CArgs aa = {xa, WT_am0, 64, 0, nullptr, nullptr, 0, 0, 1, nullptr, S2h, NA, gA};
    mfma2_k<false, true><<<gC + gA, TPB, 0, stream>>>(ac, aa);  // S = x@Wl (bf16)
  }
  gather2_k<<<gnM, TPB, 0, stream>>>(S1h, S2h, rp_m_cm, pm_m_cm, rinv_m_cm,
                                     rp_m_am, pm_m_am, rinv_m_am, NM, A);
  // A = xm1 pre-relu (bf16)

  // ---- layer 1 ----
  {
    CArgs am = {A, WT_r1, 128, 1, nullptr, nullptr, 0, 0, 1, b1c, A, NM, gM};
    mfma2_k<true, true><<<gM, TPB, 0, stream>>>(am, Z);  // in-place relu(A)@Wr1+b
  }
  {
    CArgs ac = {B, WT_cm1, 128, 1, nullptr, nullptr, 0, 0, 1, nullptr, S1h, NC, gC};
    CArgs aa = {C, WT_am1, 128, 1, nullptr, nullptr, 0, 0, 1, nullptr, S2h, NA, gA};
    mfma2_k<true, true><<<gC + gA, TPB, 0, stream>>>(ac, aa);
  }
  gather2_k<<<gnM, TPB, 0, stream>>>(S1h, S2h, rp_m_cm, pm_m_cm, rinv_m_cm,
                                     rp_m_am, pm_m_am, rinv_m_am, NM, A);
  // A = xm2 pre-relu (bf16)

  // ---- final linear ----
  final_k<<<(NM + TPB - 1) / TPB, TPB, 0, stream>>>(A, lin_W, lin_b, outf, NM);
}